// Round 1
// baseline (702.388 us; speedup 1.0000x reference)
//
#include <hip/hip_runtime.h>

// GCN: 3 layers, N=50000 nodes, E=600000 edges, feats 128->128->128->64,
// BatchNorm+ReLU between layers. norm = dis[src]*dis[dst] factorized out.

static __device__ __forceinline__ float4 ld4(const float* p) {
    return *reinterpret_cast<const float4*>(p);
}

__global__ void k_init(int* __restrict__ cnt, float* __restrict__ stats, int n) {
    int i = blockIdx.x * 256 + threadIdx.x;
    if (i < n) cnt[i] = 0;
    if (i < 512) stats[i] = 0.f;   // sum1[128], sq1[128], sum2[128], sq2[128]
}

__global__ void k_count(const int* __restrict__ dst, int* __restrict__ cnt, int e) {
    int i = blockIdx.x * 256 + threadIdx.x;
    if (i < e) atomicAdd(&cnt[dst[i]], 1);
}

// Single-block exclusive scan over cnt[n] -> offs[n+1]; also cursor=offs and
// dis[i] = rsqrt(deg) with deg = cnt[i]+1 (self-loop).
__global__ __launch_bounds__(1024) void k_scan(const int* __restrict__ cnt,
                                               int* __restrict__ offs,
                                               int* __restrict__ cursor,
                                               float* __restrict__ dis, int n) {
    __shared__ int sums[1024];
    int t = threadIdx.x;
    int per = (n + 1023) / 1024;
    int lo = t * per; if (lo > n) lo = n;
    int hi = lo + per; if (hi > n) hi = n;
    int s = 0;
    for (int i = lo; i < hi; ++i) s += cnt[i];
    sums[t] = s;
    __syncthreads();
    for (int off = 1; off < 1024; off <<= 1) {
        int v = (t >= off) ? sums[t - off] : 0;
        __syncthreads();
        sums[t] += v;
        __syncthreads();
    }
    int run = (t == 0) ? 0 : sums[t - 1];
    for (int i = lo; i < hi; ++i) {
        offs[i] = run;
        cursor[i] = run;
        int c = cnt[i];
        dis[i] = rsqrtf((float)(c + 1));
        run += c;
    }
    if (t == 1023) offs[n] = run;
}

__global__ void k_scatter(const int* __restrict__ src, const int* __restrict__ dst,
                          int* __restrict__ cursor, int* __restrict__ csr, int e) {
    int i = blockIdx.x * 256 + threadIdx.x;
    if (i < e) {
        int p = atomicAdd(&cursor[dst[i]], 1);
        csr[p] = src[i];
    }
}

// out[row][c] = dis[row] * sum_k in'(row,k) * W[k][c]
// in'(row,k) = TRANS ? relu(in*ta[k]+tc[k]) : in  (fused BN+ReLU of prev layer)
// Row-per-thread; W read at wave-uniform addresses -> scalar loads.
template <bool TRANS, int NC>
__global__ __launch_bounds__(256) void k_gemm(const float* __restrict__ in,
                                              const float* __restrict__ W,
                                              const float* __restrict__ dis,
                                              const float* __restrict__ ta,
                                              const float* __restrict__ tc,
                                              float* __restrict__ out, int n) {
    __shared__ float xs[256][33];   // pad 33 -> 2-way bank alias (free)
    const int tid = threadIdx.x;
    const int row0 = blockIdx.x * 256;
    float acc[NC];
#pragma unroll
    for (int c = 0; c < NC; ++c) acc[c] = 0.f;

    for (int kt = 0; kt < 4; ++kt) {
        __syncthreads();
#pragma unroll
        for (int it = 0; it < 8; ++it) {
            int flat = it * 256 + tid;      // 2048 float4 = 256 rows x 32 floats
            int r = flat >> 3, j = flat & 7;
            int grow = row0 + r;
            float4 v = make_float4(0.f, 0.f, 0.f, 0.f);
            if (grow < n) v = ld4(&in[grow * 128 + kt * 32 + j * 4]);
            if (TRANS) {
                int f = kt * 32 + j * 4;
                v.x = fmaxf(v.x * ta[f + 0] + tc[f + 0], 0.f);
                v.y = fmaxf(v.y * ta[f + 1] + tc[f + 1], 0.f);
                v.z = fmaxf(v.z * ta[f + 2] + tc[f + 2], 0.f);
                v.w = fmaxf(v.w * ta[f + 3] + tc[f + 3], 0.f);
            }
            xs[r][j * 4 + 0] = v.x;
            xs[r][j * 4 + 1] = v.y;
            xs[r][j * 4 + 2] = v.z;
            xs[r][j * 4 + 3] = v.w;
        }
        __syncthreads();
        for (int k = 0; k < 32; ++k) {
            float xk = xs[tid][k];
            const float* wr = &W[(kt * 32 + k) * NC];
#pragma unroll
            for (int c = 0; c < NC; ++c) acc[c] = fmaf(xk, wr[c], acc[c]);
        }
    }

    int row = row0 + tid;
    if (row < n) {
        float d = dis[row];
        float* orow = &out[row * NC];
#pragma unroll
        for (int c = 0; c < NC; c += 4) {
            float4 o = make_float4(acc[c] * d, acc[c + 1] * d,
                                   acc[c + 2] * d, acc[c + 3] * d);
            *reinterpret_cast<float4*>(&orow[c]) = o;
        }
    }
}

// One wave per node: out[i] = dis[i] * (hs[i] + sum_{src in(i)} hs[src]) + bias
template <int NC>
__global__ __launch_bounds__(256) void k_agg(const float* __restrict__ hs,
                                             const int* __restrict__ offs,
                                             const int* __restrict__ csr,
                                             const float* __restrict__ dis,
                                             const float* __restrict__ bias,
                                             float* __restrict__ out, int n) {
    int wave = threadIdx.x >> 6, lane = threadIdx.x & 63;
    int node = blockIdx.x * 4 + wave;
    if (node >= n) return;
    int e0 = offs[node], e1 = offs[node + 1];
    if (NC == 128) {
        const float2* hp = reinterpret_cast<const float2*>(hs);
        float2 acc = hp[node * 64 + lane];          // self-loop
        for (int e = e0; e < e1; ++e) {
            int s = csr[e];
            float2 v = hp[s * 64 + lane];
            acc.x += v.x;
            acc.y += v.y;
        }
        float d = dis[node];
        float2 o = make_float2(d * acc.x + bias[2 * lane],
                               d * acc.y + bias[2 * lane + 1]);
        reinterpret_cast<float2*>(out)[node * 64 + lane] = o;
    } else {
        float acc = hs[node * 64 + lane];
        for (int e = e0; e < e1; ++e) acc += hs[csr[e] * 64 + lane];
        out[node * 64 + lane] = dis[node] * acc + bias[lane];
    }
}

// Column sums / sumsq over rows (for BN stats). Block handles 256 rows.
__global__ __launch_bounds__(256) void k_stats(const float* __restrict__ h,
                                               float* __restrict__ sum,
                                               float* __restrict__ sumsq, int n) {
    __shared__ float ls[128], ls2[128];
    int c = threadIdx.x & 127, half = threadIdx.x >> 7;
    int r0 = blockIdx.x * 256;
    int rend = r0 + 256; if (rend > n) rend = n;
    float s = 0.f, s2 = 0.f;
    for (int r = r0 + half; r < rend; r += 2) {
        float v = h[r * 128 + c];
        s += v;
        s2 += v * v;
    }
    if (half == 1) { ls[c] = s; ls2[c] = s2; }
    __syncthreads();
    if (half == 0) {
        s += ls[c];
        s2 += ls2[c];
        atomicAdd(&sum[c], s);
        atomicAdd(&sumsq[c], s2);
    }
}

__global__ void k_bnparams(const float* __restrict__ sum, const float* __restrict__ sumsq,
                           const float* __restrict__ gamma, const float* __restrict__ beta,
                           float* __restrict__ a, float* __restrict__ cc, int n) {
    int c = threadIdx.x;
    if (c < 128) {
        float inv_n = 1.0f / (float)n;
        float mean = sum[c] * inv_n;
        float var = sumsq[c] * inv_n - mean * mean;
        float sc = gamma[c] * rsqrtf(var + 1e-5f);
        a[c] = sc;
        cc[c] = beta[c] - mean * sc;
    }
}

extern "C" void kernel_launch(void* const* d_in, const int* in_sizes, int n_in,
                              void* d_out, int out_size, void* d_ws, size_t ws_size,
                              hipStream_t stream) {
    const float* x      = (const float*)d_in[0];
    const int*   ei     = (const int*)d_in[1];     // [2,E] row-major: src then dst
    const float* W1     = (const float*)d_in[2];
    const float* b1     = (const float*)d_in[3];
    const float* gamma1 = (const float*)d_in[4];
    const float* beta1  = (const float*)d_in[5];
    const float* W2     = (const float*)d_in[6];
    const float* b2     = (const float*)d_in[7];
    const float* gamma2 = (const float*)d_in[8];
    const float* beta2  = (const float*)d_in[9];
    const float* W3     = (const float*)d_in[10];
    const float* b3     = (const float*)d_in[11];
    float* out = (float*)d_out;

    const int n = in_sizes[0] / 128;       // 50000
    const int e = in_sizes[1] / 2;         // 600000
    const int* esrc = ei;
    const int* edst = ei + e;

    // workspace layout (256B aligned chunks)
    char* p = (char*)d_ws;
    auto alloc = [&](size_t bytes) {
        void* r = p;
        p += (bytes + 255) & ~size_t(255);
        return r;
    };
    float* bufA   = (float*)alloc(sizeof(float) * (size_t)n * 128);
    float* bufB   = (float*)alloc(sizeof(float) * (size_t)n * 128);
    int*   cnt    = (int*)alloc(sizeof(int) * n);
    int*   offs   = (int*)alloc(sizeof(int) * (n + 1));
    int*   cursor = (int*)alloc(sizeof(int) * n);
    int*   csr    = (int*)alloc(sizeof(int) * e);
    float* dis    = (float*)alloc(sizeof(float) * n);
    float* stats  = (float*)alloc(sizeof(float) * 512);  // sum1,sq1,sum2,sq2
    float* bn     = (float*)alloc(sizeof(float) * 512);  // a1,cc1,a2,cc2
    float* sum1 = stats, *sq1 = stats + 128, *sum2 = stats + 256, *sq2 = stats + 384;
    float* a1 = bn, *cc1 = bn + 128, *a2 = bn + 256, *cc2 = bn + 384;

    int gb_n  = (n + 255) / 256;
    int gb_e  = (e + 255) / 256;
    int gb_agg = (n + 3) / 4;

    // graph preprocessing (shared by all 3 layers)
    k_init<<<gb_n, 256, 0, stream>>>(cnt, stats, n);
    k_count<<<gb_e, 256, 0, stream>>>(edst, cnt, e);
    k_scan<<<1, 1024, 0, stream>>>(cnt, offs, cursor, dis, n);
    k_scatter<<<gb_e, 256, 0, stream>>>(esrc, edst, cursor, csr, e);

    // layer 1
    k_gemm<false, 128><<<gb_n, 256, 0, stream>>>(x, W1, dis, nullptr, nullptr, bufA, n);
    k_agg<128><<<gb_agg, 256, 0, stream>>>(bufA, offs, csr, dis, b1, bufB, n);
    k_stats<<<gb_n, 256, 0, stream>>>(bufB, sum1, sq1, n);
    k_bnparams<<<1, 128, 0, stream>>>(sum1, sq1, gamma1, beta1, a1, cc1, n);

    // layer 2
    k_gemm<true, 128><<<gb_n, 256, 0, stream>>>(bufB, W2, dis, a1, cc1, bufA, n);
    k_agg<128><<<gb_agg, 256, 0, stream>>>(bufA, offs, csr, dis, b2, bufB, n);
    k_stats<<<gb_n, 256, 0, stream>>>(bufB, sum2, sq2, n);
    k_bnparams<<<1, 128, 0, stream>>>(sum2, sq2, gamma2, beta2, a2, cc2, n);

    // layer 3 (no BN/ReLU after)
    k_gemm<true, 64><<<gb_n, 256, 0, stream>>>(bufB, W3, dis, a2, cc2, bufA, n);
    k_agg<64><<<gb_agg, 256, 0, stream>>>(bufA, offs, csr, dis, b3, out, n);
}

// Round 2
// 611.252 us; speedup vs baseline: 1.1491x; 1.1491x over previous
//
#include <hip/hip_runtime.h>

// GCN: 3 layers, N=50000 nodes, E=600000 edges, feats 128->128->128->64,
// BatchNorm+ReLU between layers. norm = dis[src]*dis[dst] factorized out.

#define NCHUNK 1024

static __device__ __forceinline__ float4 ld4(const float* p) {
    return *reinterpret_cast<const float4*>(p);
}

__global__ void k_init(int* __restrict__ cnt, float* __restrict__ stats, int n) {
    int i = blockIdx.x * 256 + threadIdx.x;
    if (i < n) cnt[i] = 0;
    if (i < 512) stats[i] = 0.f;   // sum1[128], sq1[128], sum2[128], sq2[128]
}

__global__ void k_count(const int* __restrict__ dst, int* __restrict__ cnt, int e) {
    int i = blockIdx.x * 256 + threadIdx.x;
    if (i < e) atomicAdd(&cnt[dst[i]], 1);
}

// Stage 1: per-chunk sums of cnt. NCHUNK threads, chunk = contiguous run.
__global__ __launch_bounds__(256) void k_chunksum(const int* __restrict__ cnt,
                                                  int* __restrict__ chunkSum, int n) {
    int t = blockIdx.x * 256 + threadIdx.x;   // 0..NCHUNK-1
    int per = (n + NCHUNK - 1) / NCHUNK;
    int lo = t * per; if (lo > n) lo = n;
    int hi = lo + per; if (hi > n) hi = n;
    int s = 0;
    for (int i = lo; i < hi; ++i) s += cnt[i];
    chunkSum[t] = s;
}

// Stage 2: single-block exclusive scan of chunkSum[NCHUNK] -> chunkBase[NCHUNK].
__global__ __launch_bounds__(1024) void k_chunkscan(const int* __restrict__ chunkSum,
                                                    int* __restrict__ chunkBase) {
    __shared__ int sums[NCHUNK];
    int t = threadIdx.x;
    sums[t] = chunkSum[t];
    __syncthreads();
    for (int off = 1; off < NCHUNK; off <<= 1) {
        int v = (t >= off) ? sums[t - off] : 0;
        __syncthreads();
        sums[t] += v;
        __syncthreads();
    }
    chunkBase[t] = (t == 0) ? 0 : sums[t - 1];
}

// Stage 3: each thread writes offs/cursor/dis for its chunk.
__global__ __launch_bounds__(256) void k_chunkwrite(const int* __restrict__ cnt,
                                                    const int* __restrict__ chunkBase,
                                                    int* __restrict__ offs,
                                                    int* __restrict__ cursor,
                                                    float* __restrict__ dis,
                                                    int n, int e) {
    int t = blockIdx.x * 256 + threadIdx.x;   // 0..NCHUNK-1
    int per = (n + NCHUNK - 1) / NCHUNK;
    int lo = t * per; if (lo > n) lo = n;
    int hi = lo + per; if (hi > n) hi = n;
    int run = chunkBase[t];
    for (int i = lo; i < hi; ++i) {
        offs[i] = run;
        cursor[i] = run;
        int c = cnt[i];
        dis[i] = rsqrtf((float)(c + 1));
        run += c;
    }
    if (t == 0) offs[n] = e;
}

__global__ void k_scatter(const int* __restrict__ src, const int* __restrict__ dst,
                          int* __restrict__ cursor, int* __restrict__ csr, int e) {
    int i = blockIdx.x * 256 + threadIdx.x;
    if (i < e) {
        int p = atomicAdd(&cursor[dst[i]], 1);
        csr[p] = src[i];
    }
}

// out[row][c] = dis[row] * sum_k in'(row,k) * W[k][c]
// in'(row,k) = TRANS ? relu(in*ta[k]+tc[k]) : in  (fused BN+ReLU of prev layer)
// Row-per-thread; W read at wave-uniform addresses -> scalar loads.
template <bool TRANS, int NC>
__global__ __launch_bounds__(256) void k_gemm(const float* __restrict__ in,
                                              const float* __restrict__ W,
                                              const float* __restrict__ dis,
                                              const float* __restrict__ ta,
                                              const float* __restrict__ tc,
                                              float* __restrict__ out, int n) {
    __shared__ float xs[256][33];   // pad 33 -> 2-way bank alias (free)
    const int tid = threadIdx.x;
    const int row0 = blockIdx.x * 256;
    float acc[NC];
#pragma unroll
    for (int c = 0; c < NC; ++c) acc[c] = 0.f;

    for (int kt = 0; kt < 4; ++kt) {
        __syncthreads();
#pragma unroll
        for (int it = 0; it < 8; ++it) {
            int flat = it * 256 + tid;      // 2048 float4 = 256 rows x 32 floats
            int r = flat >> 3, j = flat & 7;
            int grow = row0 + r;
            float4 v = make_float4(0.f, 0.f, 0.f, 0.f);
            if (grow < n) v = ld4(&in[grow * 128 + kt * 32 + j * 4]);
            if (TRANS) {
                int f = kt * 32 + j * 4;
                v.x = fmaxf(v.x * ta[f + 0] + tc[f + 0], 0.f);
                v.y = fmaxf(v.y * ta[f + 1] + tc[f + 1], 0.f);
                v.z = fmaxf(v.z * ta[f + 2] + tc[f + 2], 0.f);
                v.w = fmaxf(v.w * ta[f + 3] + tc[f + 3], 0.f);
            }
            xs[r][j * 4 + 0] = v.x;
            xs[r][j * 4 + 1] = v.y;
            xs[r][j * 4 + 2] = v.z;
            xs[r][j * 4 + 3] = v.w;
        }
        __syncthreads();
        for (int k = 0; k < 32; ++k) {
            float xk = xs[tid][k];
            const float* wr = &W[(kt * 32 + k) * NC];
#pragma unroll
            for (int c = 0; c < NC; ++c) acc[c] = fmaf(xk, wr[c], acc[c]);
        }
    }

    int row = row0 + tid;
    if (row < n) {
        float d = dis[row];
        float* orow = &out[row * NC];
#pragma unroll
        for (int c = 0; c < NC; c += 4) {
            float4 o = make_float4(acc[c] * d, acc[c + 1] * d,
                                   acc[c + 2] * d, acc[c + 3] * d);
            *reinterpret_cast<float4*>(&orow[c]) = o;
        }
    }
}

// One wave per node: out[i] = dis[i] * (hs[i] + sum_{src in(i)} hs[src]) + bias
template <int NC>
__global__ __launch_bounds__(256) void k_agg(const float* __restrict__ hs,
                                             const int* __restrict__ offs,
                                             const int* __restrict__ csr,
                                             const float* __restrict__ dis,
                                             const float* __restrict__ bias,
                                             float* __restrict__ out, int n) {
    int wave = threadIdx.x >> 6, lane = threadIdx.x & 63;
    int node = blockIdx.x * 4 + wave;
    if (node >= n) return;
    int e0 = offs[node], e1 = offs[node + 1];
    if (NC == 128) {
        const float2* hp = reinterpret_cast<const float2*>(hs);
        float2 acc = hp[node * 64 + lane];          // self-loop
        for (int e = e0; e < e1; ++e) {
            int s = csr[e];
            float2 v = hp[s * 64 + lane];
            acc.x += v.x;
            acc.y += v.y;
        }
        float d = dis[node];
        float2 o = make_float2(d * acc.x + bias[2 * lane],
                               d * acc.y + bias[2 * lane + 1]);
        reinterpret_cast<float2*>(out)[node * 64 + lane] = o;
    } else {
        float acc = hs[node * 64 + lane];
        for (int e = e0; e < e1; ++e) acc += hs[csr[e] * 64 + lane];
        out[node * 64 + lane] = dis[node] * acc + bias[lane];
    }
}

// Column sums / sumsq over rows (for BN stats). Block handles 256 rows.
__global__ __launch_bounds__(256) void k_stats(const float* __restrict__ h,
                                               float* __restrict__ sum,
                                               float* __restrict__ sumsq, int n) {
    __shared__ float ls[128], ls2[128];
    int c = threadIdx.x & 127, half = threadIdx.x >> 7;
    int r0 = blockIdx.x * 256;
    int rend = r0 + 256; if (rend > n) rend = n;
    float s = 0.f, s2 = 0.f;
    for (int r = r0 + half; r < rend; r += 2) {
        float v = h[r * 128 + c];
        s += v;
        s2 += v * v;
    }
    if (half == 1) { ls[c] = s; ls2[c] = s2; }
    __syncthreads();
    if (half == 0) {
        s += ls[c];
        s2 += ls2[c];
        atomicAdd(&sum[c], s);
        atomicAdd(&sumsq[c], s2);
    }
}

__global__ void k_bnparams(const float* __restrict__ sum, const float* __restrict__ sumsq,
                           const float* __restrict__ gamma, const float* __restrict__ beta,
                           float* __restrict__ a, float* __restrict__ cc, int n) {
    int c = threadIdx.x;
    if (c < 128) {
        float inv_n = 1.0f / (float)n;
        float mean = sum[c] * inv_n;
        float var = sumsq[c] * inv_n - mean * mean;
        float sc = gamma[c] * rsqrtf(var + 1e-5f);
        a[c] = sc;
        cc[c] = beta[c] - mean * sc;
    }
}

extern "C" void kernel_launch(void* const* d_in, const int* in_sizes, int n_in,
                              void* d_out, int out_size, void* d_ws, size_t ws_size,
                              hipStream_t stream) {
    const float* x      = (const float*)d_in[0];
    const int*   ei     = (const int*)d_in[1];     // [2,E] row-major: src then dst
    const float* W1     = (const float*)d_in[2];
    const float* b1     = (const float*)d_in[3];
    const float* gamma1 = (const float*)d_in[4];
    const float* beta1  = (const float*)d_in[5];
    const float* W2     = (const float*)d_in[6];
    const float* b2     = (const float*)d_in[7];
    const float* gamma2 = (const float*)d_in[8];
    const float* beta2  = (const float*)d_in[9];
    const float* W3     = (const float*)d_in[10];
    const float* b3     = (const float*)d_in[11];
    float* out = (float*)d_out;

    const int n = in_sizes[0] / 128;       // 50000
    const int e = in_sizes[1] / 2;         // 600000
    const int* esrc = ei;
    const int* edst = ei + e;

    // workspace layout (256B aligned chunks)
    char* p = (char*)d_ws;
    auto alloc = [&](size_t bytes) {
        void* r = p;
        p += (bytes + 255) & ~size_t(255);
        return r;
    };
    float* bufA   = (float*)alloc(sizeof(float) * (size_t)n * 128);
    float* bufB   = (float*)alloc(sizeof(float) * (size_t)n * 128);
    int*   cnt    = (int*)alloc(sizeof(int) * n);
    int*   offs   = (int*)alloc(sizeof(int) * (n + 1));
    int*   cursor = (int*)alloc(sizeof(int) * n);
    int*   csr    = (int*)alloc(sizeof(int) * e);
    float* dis    = (float*)alloc(sizeof(float) * n);
    float* stats  = (float*)alloc(sizeof(float) * 512);  // sum1,sq1,sum2,sq2
    float* bn     = (float*)alloc(sizeof(float) * 512);  // a1,cc1,a2,cc2
    int*   chunkSum  = (int*)alloc(sizeof(int) * NCHUNK);
    int*   chunkBase = (int*)alloc(sizeof(int) * NCHUNK);
    float* sum1 = stats, *sq1 = stats + 128, *sum2 = stats + 256, *sq2 = stats + 384;
    float* a1 = bn, *cc1 = bn + 128, *a2 = bn + 256, *cc2 = bn + 384;

    int gb_n  = (n + 255) / 256;
    int gb_e  = (e + 255) / 256;
    int gb_agg = (n + 3) / 4;

    // graph preprocessing (shared by all 3 layers)
    k_init<<<gb_n, 256, 0, stream>>>(cnt, stats, n);
    k_count<<<gb_e, 256, 0, stream>>>(edst, cnt, e);
    k_chunksum<<<NCHUNK / 256, 256, 0, stream>>>(cnt, chunkSum, n);
    k_chunkscan<<<1, NCHUNK, 0, stream>>>(chunkSum, chunkBase);
    k_chunkwrite<<<NCHUNK / 256, 256, 0, stream>>>(cnt, chunkBase, offs, cursor, dis, n, e);
    k_scatter<<<gb_e, 256, 0, stream>>>(esrc, edst, cursor, csr, e);

    // layer 1
    k_gemm<false, 128><<<gb_n, 256, 0, stream>>>(x, W1, dis, nullptr, nullptr, bufA, n);
    k_agg<128><<<gb_agg, 256, 0, stream>>>(bufA, offs, csr, dis, b1, bufB, n);
    k_stats<<<gb_n, 256, 0, stream>>>(bufB, sum1, sq1, n);
    k_bnparams<<<1, 128, 0, stream>>>(sum1, sq1, gamma1, beta1, a1, cc1, n);

    // layer 2
    k_gemm<true, 128><<<gb_n, 256, 0, stream>>>(bufB, W2, dis, a1, cc1, bufA, n);
    k_agg<128><<<gb_agg, 256, 0, stream>>>(bufA, offs, csr, dis, b2, bufB, n);
    k_stats<<<gb_n, 256, 0, stream>>>(bufB, sum2, sq2, n);
    k_bnparams<<<1, 128, 0, stream>>>(sum2, sq2, gamma2, beta2, a2, cc2, n);

    // layer 3 (no BN/ReLU after)
    k_gemm<true, 64><<<gb_n, 256, 0, stream>>>(bufB, W3, dis, a2, cc2, bufA, n);
    k_agg<64><<<gb_agg, 256, 0, stream>>>(bufA, offs, csr, dis, b3, out, n);
}

// Round 3
// 463.175 us; speedup vs baseline: 1.5165x; 1.3197x over previous
//
#include <hip/hip_runtime.h>

// GCN: 3 layers, N=50000 nodes, E=600000 edges, feats 128->128->128->64,
// BatchNorm+ReLU between layers. norm = dis[src]*dis[dst] factorized out.

#define NCHUNK 1024

static __device__ __forceinline__ float4 ld4(const float* p) {
    return *reinterpret_cast<const float4*>(p);
}

__global__ void k_init(int* __restrict__ cnt, float* __restrict__ stats, int n) {
    int i = blockIdx.x * 256 + threadIdx.x;
    if (i < n) cnt[i] = 0;
    if (i < 512) stats[i] = 0.f;   // sum1[128], sq1[128], sum2[128], sq2[128]
}

__global__ void k_count(const int* __restrict__ dst, int* __restrict__ cnt, int e) {
    int i = blockIdx.x * 256 + threadIdx.x;
    if (i < e) atomicAdd(&cnt[dst[i]], 1);
}

// Stage 1: per-chunk sums of cnt. NCHUNK threads, chunk = contiguous run.
__global__ __launch_bounds__(256) void k_chunksum(const int* __restrict__ cnt,
                                                  int* __restrict__ chunkSum, int n) {
    int t = blockIdx.x * 256 + threadIdx.x;   // 0..NCHUNK-1
    int per = (n + NCHUNK - 1) / NCHUNK;
    int lo = t * per; if (lo > n) lo = n;
    int hi = lo + per; if (hi > n) hi = n;
    int s = 0;
    for (int i = lo; i < hi; ++i) s += cnt[i];
    chunkSum[t] = s;
}

// Stage 2: single-block exclusive scan of chunkSum[NCHUNK] -> chunkBase[NCHUNK].
__global__ __launch_bounds__(1024) void k_chunkscan(const int* __restrict__ chunkSum,
                                                    int* __restrict__ chunkBase) {
    __shared__ int sums[NCHUNK];
    int t = threadIdx.x;
    sums[t] = chunkSum[t];
    __syncthreads();
    for (int off = 1; off < NCHUNK; off <<= 1) {
        int v = (t >= off) ? sums[t - off] : 0;
        __syncthreads();
        sums[t] += v;
        __syncthreads();
    }
    chunkBase[t] = (t == 0) ? 0 : sums[t - 1];
}

// Stage 3: each thread writes offs/cursor/dis for its chunk.
__global__ __launch_bounds__(256) void k_chunkwrite(const int* __restrict__ cnt,
                                                    const int* __restrict__ chunkBase,
                                                    int* __restrict__ offs,
                                                    int* __restrict__ cursor,
                                                    float* __restrict__ dis,
                                                    int n, int e) {
    int t = blockIdx.x * 256 + threadIdx.x;   // 0..NCHUNK-1
    int per = (n + NCHUNK - 1) / NCHUNK;
    int lo = t * per; if (lo > n) lo = n;
    int hi = lo + per; if (hi > n) hi = n;
    int run = chunkBase[t];
    for (int i = lo; i < hi; ++i) {
        offs[i] = run;
        cursor[i] = run;
        int c = cnt[i];
        dis[i] = rsqrtf((float)(c + 1));
        run += c;
    }
    if (t == 0) offs[n] = e;
}

__global__ void k_scatter(const int* __restrict__ src, const int* __restrict__ dst,
                          int* __restrict__ cursor, int* __restrict__ csr, int e) {
    int i = blockIdx.x * 256 + threadIdx.x;
    if (i < e) {
        int p = atomicAdd(&cursor[dst[i]], 1);
        csr[p] = src[i];
    }
}

// out[row][c] = dis[row] * sum_k in'(row,k) * W[k][c]
// in'(row,k) = TRANS ? relu(in*ta[k]+tc[k]) : in  (fused BN+ReLU of prev layer)
//
// Block: 64 rows x all NC cols. 256 threads = 4 waves; wave w owns cols
// [w*NC/4, (w+1)*NC/4), lane l owns row l. Input tile staged once in LDS
// [64][129] (pad 129 -> read bank (lane+k)%32, 2-way alias = free). W reads
// are wave-uniform (readfirstlane) -> scalar loads through constant cache.
template <bool TRANS, int NC>
__global__ __launch_bounds__(256) void k_gemm(const float* __restrict__ in,
                                              const float* __restrict__ W,
                                              const float* __restrict__ dis,
                                              const float* __restrict__ ta,
                                              const float* __restrict__ tc,
                                              float* __restrict__ out, int n) {
    constexpr int CGW = NC / 4;           // cols per wave: 32 or 16
    __shared__ float xs[64][129];
    const int tid = threadIdx.x;
    const int row0 = blockIdx.x * 64;

    // stage [64][128] tile: 2048 float4, 8 per thread, coalesced
#pragma unroll
    for (int it = 0; it < 8; ++it) {
        int flat = it * 256 + tid;
        int r = flat >> 5, j = flat & 31;     // j indexes float4 within row
        int grow = row0 + r;
        float4 v = make_float4(0.f, 0.f, 0.f, 0.f);
        if (grow < n) v = ld4(&in[grow * 128 + j * 4]);
        if (TRANS) {
            int f = j * 4;
            float4 A = ld4(&ta[f]);
            float4 C = ld4(&tc[f]);
            v.x = fmaxf(v.x * A.x + C.x, 0.f);
            v.y = fmaxf(v.y * A.y + C.y, 0.f);
            v.z = fmaxf(v.z * A.z + C.z, 0.f);
            v.w = fmaxf(v.w * A.w + C.w, 0.f);
        }
        xs[r][j * 4 + 0] = v.x;
        xs[r][j * 4 + 1] = v.y;
        xs[r][j * 4 + 2] = v.z;
        xs[r][j * 4 + 3] = v.w;
    }
    __syncthreads();

    const int lane = tid & 63;
    const int c0 = __builtin_amdgcn_readfirstlane((tid >> 6) * CGW);

    float acc[CGW];
#pragma unroll
    for (int c = 0; c < CGW; ++c) acc[c] = 0.f;

#pragma unroll 4
    for (int k = 0; k < 128; ++k) {
        float xk = xs[lane][k];
        const float* wr = &W[k * NC + c0];
#pragma unroll
        for (int c = 0; c < CGW; ++c) acc[c] = fmaf(xk, wr[c], acc[c]);
    }

    int row = row0 + lane;
    if (row < n) {
        float d = dis[row];
        float* orow = &out[row * NC + c0];
#pragma unroll
        for (int c = 0; c < CGW; c += 4) {
            float4 o = make_float4(acc[c] * d, acc[c + 1] * d,
                                   acc[c + 2] * d, acc[c + 3] * d);
            *reinterpret_cast<float4*>(&orow[c]) = o;
        }
    }
}

// One wave per node: out[i] = dis[i] * (hs[i] + sum_{src in(i)} hs[src]) + bias
template <int NC>
__global__ __launch_bounds__(256) void k_agg(const float* __restrict__ hs,
                                             const int* __restrict__ offs,
                                             const int* __restrict__ csr,
                                             const float* __restrict__ dis,
                                             const float* __restrict__ bias,
                                             float* __restrict__ out, int n) {
    int wave = threadIdx.x >> 6, lane = threadIdx.x & 63;
    int node = blockIdx.x * 4 + wave;
    if (node >= n) return;
    int e0 = offs[node], e1 = offs[node + 1];
    if (NC == 128) {
        const float2* hp = reinterpret_cast<const float2*>(hs);
        float2 acc = hp[node * 64 + lane];          // self-loop
        for (int e = e0; e < e1; ++e) {
            int s = csr[e];
            float2 v = hp[s * 64 + lane];
            acc.x += v.x;
            acc.y += v.y;
        }
        float d = dis[node];
        float2 o = make_float2(d * acc.x + bias[2 * lane],
                               d * acc.y + bias[2 * lane + 1]);
        reinterpret_cast<float2*>(out)[node * 64 + lane] = o;
    } else {
        float acc = hs[node * 64 + lane];
        for (int e = e0; e < e1; ++e) acc += hs[csr[e] * 64 + lane];
        out[node * 64 + lane] = dis[node] * acc + bias[lane];
    }
}

// Column sums / sumsq over rows (for BN stats). Block handles 256 rows.
__global__ __launch_bounds__(256) void k_stats(const float* __restrict__ h,
                                               float* __restrict__ sum,
                                               float* __restrict__ sumsq, int n) {
    __shared__ float ls[128], ls2[128];
    int c = threadIdx.x & 127, half = threadIdx.x >> 7;
    int r0 = blockIdx.x * 256;
    int rend = r0 + 256; if (rend > n) rend = n;
    float s = 0.f, s2 = 0.f;
    for (int r = r0 + half; r < rend; r += 2) {
        float v = h[r * 128 + c];
        s += v;
        s2 += v * v;
    }
    if (half == 1) { ls[c] = s; ls2[c] = s2; }
    __syncthreads();
    if (half == 0) {
        s += ls[c];
        s2 += ls2[c];
        atomicAdd(&sum[c], s);
        atomicAdd(&sumsq[c], s2);
    }
}

__global__ void k_bnparams(const float* __restrict__ sum, const float* __restrict__ sumsq,
                           const float* __restrict__ gamma, const float* __restrict__ beta,
                           float* __restrict__ a, float* __restrict__ cc, int n) {
    int c = threadIdx.x;
    if (c < 128) {
        float inv_n = 1.0f / (float)n;
        float mean = sum[c] * inv_n;
        float var = sumsq[c] * inv_n - mean * mean;
        float sc = gamma[c] * rsqrtf(var + 1e-5f);
        a[c] = sc;
        cc[c] = beta[c] - mean * sc;
    }
}

extern "C" void kernel_launch(void* const* d_in, const int* in_sizes, int n_in,
                              void* d_out, int out_size, void* d_ws, size_t ws_size,
                              hipStream_t stream) {
    const float* x      = (const float*)d_in[0];
    const int*   ei     = (const int*)d_in[1];     // [2,E] row-major: src then dst
    const float* W1     = (const float*)d_in[2];
    const float* b1     = (const float*)d_in[3];
    const float* gamma1 = (const float*)d_in[4];
    const float* beta1  = (const float*)d_in[5];
    const float* W2     = (const float*)d_in[6];
    const float* b2     = (const float*)d_in[7];
    const float* gamma2 = (const float*)d_in[8];
    const float* beta2  = (const float*)d_in[9];
    const float* W3     = (const float*)d_in[10];
    const float* b3     = (const float*)d_in[11];
    float* out = (float*)d_out;

    const int n = in_sizes[0] / 128;       // 50000
    const int e = in_sizes[1] / 2;         // 600000
    const int* esrc = ei;
    const int* edst = ei + e;

    // workspace layout (256B aligned chunks)
    char* p = (char*)d_ws;
    auto alloc = [&](size_t bytes) {
        void* r = p;
        p += (bytes + 255) & ~size_t(255);
        return r;
    };
    float* bufA   = (float*)alloc(sizeof(float) * (size_t)n * 128);
    float* bufB   = (float*)alloc(sizeof(float) * (size_t)n * 128);
    int*   cnt    = (int*)alloc(sizeof(int) * n);
    int*   offs   = (int*)alloc(sizeof(int) * (n + 1));
    int*   cursor = (int*)alloc(sizeof(int) * n);
    int*   csr    = (int*)alloc(sizeof(int) * e);
    float* dis    = (float*)alloc(sizeof(float) * n);
    float* stats  = (float*)alloc(sizeof(float) * 512);  // sum1,sq1,sum2,sq2
    float* bn     = (float*)alloc(sizeof(float) * 512);  // a1,cc1,a2,cc2
    int*   chunkSum  = (int*)alloc(sizeof(int) * NCHUNK);
    int*   chunkBase = (int*)alloc(sizeof(int) * NCHUNK);
    float* sum1 = stats, *sq1 = stats + 128, *sum2 = stats + 256, *sq2 = stats + 384;
    float* a1 = bn, *cc1 = bn + 128, *a2 = bn + 256, *cc2 = bn + 384;

    int gb_n  = (n + 255) / 256;
    int gb_e  = (e + 255) / 256;
    int gb_gemm = (n + 63) / 64;
    int gb_agg = (n + 3) / 4;

    // graph preprocessing (shared by all 3 layers)
    k_init<<<gb_n, 256, 0, stream>>>(cnt, stats, n);
    k_count<<<gb_e, 256, 0, stream>>>(edst, cnt, e);
    k_chunksum<<<NCHUNK / 256, 256, 0, stream>>>(cnt, chunkSum, n);
    k_chunkscan<<<1, NCHUNK, 0, stream>>>(chunkSum, chunkBase);
    k_chunkwrite<<<NCHUNK / 256, 256, 0, stream>>>(cnt, chunkBase, offs, cursor, dis, n, e);
    k_scatter<<<gb_e, 256, 0, stream>>>(esrc, edst, cursor, csr, e);

    // layer 1
    k_gemm<false, 128><<<gb_gemm, 256, 0, stream>>>(x, W1, dis, nullptr, nullptr, bufA, n);
    k_agg<128><<<gb_agg, 256, 0, stream>>>(bufA, offs, csr, dis, b1, bufB, n);
    k_stats<<<gb_n, 256, 0, stream>>>(bufB, sum1, sq1, n);
    k_bnparams<<<1, 128, 0, stream>>>(sum1, sq1, gamma1, beta1, a1, cc1, n);

    // layer 2
    k_gemm<true, 128><<<gb_gemm, 256, 0, stream>>>(bufB, W2, dis, a1, cc1, bufA, n);
    k_agg<128><<<gb_agg, 256, 0, stream>>>(bufA, offs, csr, dis, b2, bufB, n);
    k_stats<<<gb_n, 256, 0, stream>>>(bufB, sum2, sq2, n);
    k_bnparams<<<1, 128, 0, stream>>>(sum2, sq2, gamma2, beta2, a2, cc2, n);

    // layer 3 (no BN/ReLU after)
    k_gemm<true, 64><<<gb_gemm, 256, 0, stream>>>(bufB, W3, dis, a2, cc2, bufA, n);
    k_agg<64><<<gb_agg, 256, 0, stream>>>(bufA, offs, csr, dis, b3, out, n);
}

// Round 4
// 389.440 us; speedup vs baseline: 1.8036x; 1.1893x over previous
//
#include <hip/hip_runtime.h>

// GCN: 3 layers, N=50000 nodes, E=600000 edges, feats 128->128->128->64,
// BatchNorm+ReLU between layers. norm = dis[src]*dis[dst] factorized out.

#define NCHUNK 1024

static __device__ __forceinline__ float4 ld4(const float* p) {
    return *reinterpret_cast<const float4*>(p);
}

__global__ void k_init(int* __restrict__ cnt, float* __restrict__ stats, int n) {
    int i = blockIdx.x * 256 + threadIdx.x;
    if (i < n) cnt[i] = 0;
    if (i < 512) stats[i] = 0.f;   // sum1[128], sq1[128], sum2[128], sq2[128]
}

__global__ void k_count(const int* __restrict__ dst, int* __restrict__ cnt, int e) {
    int i = blockIdx.x * 256 + threadIdx.x;
    if (i < e) atomicAdd(&cnt[dst[i]], 1);
}

// Stage 1: per-chunk sums of cnt. NCHUNK threads, chunk = contiguous run.
__global__ __launch_bounds__(256) void k_chunksum(const int* __restrict__ cnt,
                                                  int* __restrict__ chunkSum, int n) {
    int t = blockIdx.x * 256 + threadIdx.x;   // 0..NCHUNK-1
    int per = (n + NCHUNK - 1) / NCHUNK;
    int lo = t * per; if (lo > n) lo = n;
    int hi = lo + per; if (hi > n) hi = n;
    int s = 0;
    for (int i = lo; i < hi; ++i) s += cnt[i];
    chunkSum[t] = s;
}

// Stage 2: single-block exclusive scan of chunkSum[NCHUNK] -> chunkBase[NCHUNK].
__global__ __launch_bounds__(1024) void k_chunkscan(const int* __restrict__ chunkSum,
                                                    int* __restrict__ chunkBase) {
    __shared__ int sums[NCHUNK];
    int t = threadIdx.x;
    sums[t] = chunkSum[t];
    __syncthreads();
    for (int off = 1; off < NCHUNK; off <<= 1) {
        int v = (t >= off) ? sums[t - off] : 0;
        __syncthreads();
        sums[t] += v;
        __syncthreads();
    }
    chunkBase[t] = (t == 0) ? 0 : sums[t - 1];
}

// Stage 3: each thread writes offs/cursor/dis for its chunk.
__global__ __launch_bounds__(256) void k_chunkwrite(const int* __restrict__ cnt,
                                                    const int* __restrict__ chunkBase,
                                                    int* __restrict__ offs,
                                                    int* __restrict__ cursor,
                                                    float* __restrict__ dis,
                                                    int n, int e) {
    int t = blockIdx.x * 256 + threadIdx.x;   // 0..NCHUNK-1
    int per = (n + NCHUNK - 1) / NCHUNK;
    int lo = t * per; if (lo > n) lo = n;
    int hi = lo + per; if (hi > n) hi = n;
    int run = chunkBase[t];
    for (int i = lo; i < hi; ++i) {
        offs[i] = run;
        cursor[i] = run;
        int c = cnt[i];
        dis[i] = rsqrtf((float)(c + 1));
        run += c;
    }
    if (t == 0) offs[n] = e;
}

__global__ void k_scatter(const int* __restrict__ src, const int* __restrict__ dst,
                          int* __restrict__ cursor, int* __restrict__ csr, int e) {
    int i = blockIdx.x * 256 + threadIdx.x;
    if (i < e) {
        int p = atomicAdd(&cursor[dst[i]], 1);
        csr[p] = src[i];
    }
}

// out[row][c] = dis[row] * sum_k in'(row,k) * W[k][c]
// in'(row,k) = TRANS ? relu(in*ta[k]+tc[k]) : in  (fused BN+ReLU of prev layer)
//
// Block: 64 rows x all NC cols. 256 threads = 4 waves; wave w owns cols
// [w*NC/4, (w+1)*NC/4), lane l owns row l. Input tile staged once in LDS
// [64][129] (pad 129 -> read bank (lane+k)%32, 2-way alias = free). W reads
// are wave-uniform (readfirstlane) -> scalar loads through constant cache.
template <bool TRANS, int NC>
__global__ __launch_bounds__(256) void k_gemm(const float* __restrict__ in,
                                              const float* __restrict__ W,
                                              const float* __restrict__ dis,
                                              const float* __restrict__ ta,
                                              const float* __restrict__ tc,
                                              float* __restrict__ out, int n) {
    constexpr int CGW = NC / 4;           // cols per wave: 32 or 16
    __shared__ float xs[64][129];
    const int tid = threadIdx.x;
    const int row0 = blockIdx.x * 64;

    // stage [64][128] tile: 2048 float4, 8 per thread, coalesced
#pragma unroll
    for (int it = 0; it < 8; ++it) {
        int flat = it * 256 + tid;
        int r = flat >> 5, j = flat & 31;     // j indexes float4 within row
        int grow = row0 + r;
        float4 v = make_float4(0.f, 0.f, 0.f, 0.f);
        if (grow < n) v = ld4(&in[grow * 128 + j * 4]);
        if (TRANS) {
            int f = j * 4;
            float4 A = ld4(&ta[f]);
            float4 C = ld4(&tc[f]);
            v.x = fmaxf(v.x * A.x + C.x, 0.f);
            v.y = fmaxf(v.y * A.y + C.y, 0.f);
            v.z = fmaxf(v.z * A.z + C.z, 0.f);
            v.w = fmaxf(v.w * A.w + C.w, 0.f);
        }
        xs[r][j * 4 + 0] = v.x;
        xs[r][j * 4 + 1] = v.y;
        xs[r][j * 4 + 2] = v.z;
        xs[r][j * 4 + 3] = v.w;
    }
    __syncthreads();

    const int lane = tid & 63;
    const int c0 = __builtin_amdgcn_readfirstlane((tid >> 6) * CGW);

    float acc[CGW];
#pragma unroll
    for (int c = 0; c < CGW; ++c) acc[c] = 0.f;

#pragma unroll 4
    for (int k = 0; k < 128; ++k) {
        float xk = xs[lane][k];
        const float* wr = &W[k * NC + c0];
#pragma unroll
        for (int c = 0; c < CGW; ++c) acc[c] = fmaf(xk, wr[c], acc[c]);
    }

    int row = row0 + lane;
    if (row < n) {
        float d = dis[row];
        float* orow = &out[row * NC + c0];
#pragma unroll
        for (int c = 0; c < CGW; c += 4) {
            float4 o = make_float4(acc[c] * d, acc[c + 1] * d,
                                   acc[c + 2] * d, acc[c + 3] * d);
            *reinterpret_cast<float4*>(&orow[c]) = o;
        }
    }
}

// One wave per node: out[i] = dis[i] * (hs[i] + sum_{src in(i)} hs[src]) + bias
// High-MLP layout: NC=128 -> 32 lanes x float4 per row, 2 edges/wave-step
// (half = lane>>5), main loop 8 edges/iter with 4 independent accumulators
// -> 4 row-loads in flight per wave. NC=64 -> same with float2.
template <int NC>
__global__ __launch_bounds__(256) void k_agg(const float* __restrict__ hs,
                                             const int* __restrict__ offs,
                                             const int* __restrict__ csr,
                                             const float* __restrict__ dis,
                                             const float* __restrict__ bias,
                                             float* __restrict__ out, int n) {
    int wave = threadIdx.x >> 6, lane = threadIdx.x & 63;
    int node = blockIdx.x * 4 + wave;
    if (node >= n) return;
    const int e0 = offs[node], e1 = offs[node + 1];
    const int half = lane >> 5, l32 = lane & 31;

    if (NC == 128) {
        const float4* hp = reinterpret_cast<const float4*>(hs);
        float4 a0 = make_float4(0.f, 0.f, 0.f, 0.f);
        float4 a1 = a0, a2 = a0, a3 = a0;
        if (half == 0) a0 = hp[(size_t)node * 32 + l32];   // self-loop
        int e = e0;
        for (; e + 8 <= e1; e += 8) {
            int i0 = csr[e + 0 + half];
            int i1 = csr[e + 2 + half];
            int i2 = csr[e + 4 + half];
            int i3 = csr[e + 6 + half];
            float4 v0 = hp[(size_t)i0 * 32 + l32];
            float4 v1 = hp[(size_t)i1 * 32 + l32];
            float4 v2 = hp[(size_t)i2 * 32 + l32];
            float4 v3 = hp[(size_t)i3 * 32 + l32];
            a0.x += v0.x; a0.y += v0.y; a0.z += v0.z; a0.w += v0.w;
            a1.x += v1.x; a1.y += v1.y; a1.z += v1.z; a1.w += v1.w;
            a2.x += v2.x; a2.y += v2.y; a2.z += v2.z; a2.w += v2.w;
            a3.x += v3.x; a3.y += v3.y; a3.z += v3.z; a3.w += v3.w;
        }
        for (; e + 2 <= e1; e += 2) {
            int i0 = csr[e + half];
            float4 v0 = hp[(size_t)i0 * 32 + l32];
            a0.x += v0.x; a0.y += v0.y; a0.z += v0.z; a0.w += v0.w;
        }
        if (e < e1 && half == 0) {
            int i0 = csr[e];
            float4 v0 = hp[(size_t)i0 * 32 + l32];
            a0.x += v0.x; a0.y += v0.y; a0.z += v0.z; a0.w += v0.w;
        }
        a0.x += a1.x + a2.x + a3.x;
        a0.y += a1.y + a2.y + a3.y;
        a0.z += a1.z + a2.z + a3.z;
        a0.w += a1.w + a2.w + a3.w;
        // cross-half combine
        a0.x += __shfl_down(a0.x, 32);
        a0.y += __shfl_down(a0.y, 32);
        a0.z += __shfl_down(a0.z, 32);
        a0.w += __shfl_down(a0.w, 32);
        if (half == 0) {
            float d = dis[node];
            float4 b = ld4(&bias[l32 * 4]);
            float4 o = make_float4(d * a0.x + b.x, d * a0.y + b.y,
                                   d * a0.z + b.z, d * a0.w + b.w);
            reinterpret_cast<float4*>(out)[(size_t)node * 32 + l32] = o;
        }
    } else {
        const float2* hp = reinterpret_cast<const float2*>(hs);
        float2 a0 = make_float2(0.f, 0.f);
        float2 a1 = a0, a2 = a0, a3 = a0;
        if (half == 0) a0 = hp[(size_t)node * 32 + l32];   // self-loop
        int e = e0;
        for (; e + 8 <= e1; e += 8) {
            int i0 = csr[e + 0 + half];
            int i1 = csr[e + 2 + half];
            int i2 = csr[e + 4 + half];
            int i3 = csr[e + 6 + half];
            float2 v0 = hp[(size_t)i0 * 32 + l32];
            float2 v1 = hp[(size_t)i1 * 32 + l32];
            float2 v2 = hp[(size_t)i2 * 32 + l32];
            float2 v3 = hp[(size_t)i3 * 32 + l32];
            a0.x += v0.x; a0.y += v0.y;
            a1.x += v1.x; a1.y += v1.y;
            a2.x += v2.x; a2.y += v2.y;
            a3.x += v3.x; a3.y += v3.y;
        }
        for (; e + 2 <= e1; e += 2) {
            int i0 = csr[e + half];
            float2 v0 = hp[(size_t)i0 * 32 + l32];
            a0.x += v0.x; a0.y += v0.y;
        }
        if (e < e1 && half == 0) {
            int i0 = csr[e];
            float2 v0 = hp[(size_t)i0 * 32 + l32];
            a0.x += v0.x; a0.y += v0.y;
        }
        a0.x += a1.x + a2.x + a3.x;
        a0.y += a1.y + a2.y + a3.y;
        a0.x += __shfl_down(a0.x, 32);
        a0.y += __shfl_down(a0.y, 32);
        if (half == 0) {
            float d = dis[node];
            float2 o = make_float2(d * a0.x + bias[l32 * 2],
                                   d * a0.y + bias[l32 * 2 + 1]);
            reinterpret_cast<float2*>(out)[(size_t)node * 32 + l32] = o;
        }
    }
}

// Column sums / sumsq over rows (for BN stats). Block handles 256 rows.
__global__ __launch_bounds__(256) void k_stats(const float* __restrict__ h,
                                               float* __restrict__ sum,
                                               float* __restrict__ sumsq, int n) {
    __shared__ float ls[128], ls2[128];
    int c = threadIdx.x & 127, half = threadIdx.x >> 7;
    int r0 = blockIdx.x * 256;
    int rend = r0 + 256; if (rend > n) rend = n;
    float s = 0.f, s2 = 0.f;
    for (int r = r0 + half; r < rend; r += 2) {
        float v = h[r * 128 + c];
        s += v;
        s2 += v * v;
    }
    if (half == 1) { ls[c] = s; ls2[c] = s2; }
    __syncthreads();
    if (half == 0) {
        s += ls[c];
        s2 += ls2[c];
        atomicAdd(&sum[c], s);
        atomicAdd(&sumsq[c], s2);
    }
}

__global__ void k_bnparams(const float* __restrict__ sum, const float* __restrict__ sumsq,
                           const float* __restrict__ gamma, const float* __restrict__ beta,
                           float* __restrict__ a, float* __restrict__ cc, int n) {
    int c = threadIdx.x;
    if (c < 128) {
        float inv_n = 1.0f / (float)n;
        float mean = sum[c] * inv_n;
        float var = sumsq[c] * inv_n - mean * mean;
        float sc = gamma[c] * rsqrtf(var + 1e-5f);
        a[c] = sc;
        cc[c] = beta[c] - mean * sc;
    }
}

extern "C" void kernel_launch(void* const* d_in, const int* in_sizes, int n_in,
                              void* d_out, int out_size, void* d_ws, size_t ws_size,
                              hipStream_t stream) {
    const float* x      = (const float*)d_in[0];
    const int*   ei     = (const int*)d_in[1];     // [2,E] row-major: src then dst
    const float* W1     = (const float*)d_in[2];
    const float* b1     = (const float*)d_in[3];
    const float* gamma1 = (const float*)d_in[4];
    const float* beta1  = (const float*)d_in[5];
    const float* W2     = (const float*)d_in[6];
    const float* b2     = (const float*)d_in[7];
    const float* gamma2 = (const float*)d_in[8];
    const float* beta2  = (const float*)d_in[9];
    const float* W3     = (const float*)d_in[10];
    const float* b3     = (const float*)d_in[11];
    float* out = (float*)d_out;

    const int n = in_sizes[0] / 128;       // 50000
    const int e = in_sizes[1] / 2;         // 600000
    const int* esrc = ei;
    const int* edst = ei + e;

    // workspace layout (256B aligned chunks)
    char* p = (char*)d_ws;
    auto alloc = [&](size_t bytes) {
        void* r = p;
        p += (bytes + 255) & ~size_t(255);
        return r;
    };
    float* bufA   = (float*)alloc(sizeof(float) * (size_t)n * 128);
    float* bufB   = (float*)alloc(sizeof(float) * (size_t)n * 128);
    int*   cnt    = (int*)alloc(sizeof(int) * n);
    int*   offs   = (int*)alloc(sizeof(int) * (n + 1));
    int*   cursor = (int*)alloc(sizeof(int) * n);
    int*   csr    = (int*)alloc(sizeof(int) * e);
    float* dis    = (float*)alloc(sizeof(float) * n);
    float* stats  = (float*)alloc(sizeof(float) * 512);  // sum1,sq1,sum2,sq2
    float* bn     = (float*)alloc(sizeof(float) * 512);  // a1,cc1,a2,cc2
    int*   chunkSum  = (int*)alloc(sizeof(int) * NCHUNK);
    int*   chunkBase = (int*)alloc(sizeof(int) * NCHUNK);
    float* sum1 = stats, *sq1 = stats + 128, *sum2 = stats + 256, *sq2 = stats + 384;
    float* a1 = bn, *cc1 = bn + 128, *a2 = bn + 256, *cc2 = bn + 384;

    int gb_n  = (n + 255) / 256;
    int gb_e  = (e + 255) / 256;
    int gb_gemm = (n + 63) / 64;
    int gb_agg = (n + 3) / 4;

    // graph preprocessing (shared by all 3 layers)
    k_init<<<gb_n, 256, 0, stream>>>(cnt, stats, n);
    k_count<<<gb_e, 256, 0, stream>>>(edst, cnt, e);
    k_chunksum<<<NCHUNK / 256, 256, 0, stream>>>(cnt, chunkSum, n);
    k_chunkscan<<<1, NCHUNK, 0, stream>>>(chunkSum, chunkBase);
    k_chunkwrite<<<NCHUNK / 256, 256, 0, stream>>>(cnt, chunkBase, offs, cursor, dis, n, e);
    k_scatter<<<gb_e, 256, 0, stream>>>(esrc, edst, cursor, csr, e);

    // layer 1
    k_gemm<false, 128><<<gb_gemm, 256, 0, stream>>>(x, W1, dis, nullptr, nullptr, bufA, n);
    k_agg<128><<<gb_agg, 256, 0, stream>>>(bufA, offs, csr, dis, b1, bufB, n);
    k_stats<<<gb_n, 256, 0, stream>>>(bufB, sum1, sq1, n);
    k_bnparams<<<1, 128, 0, stream>>>(sum1, sq1, gamma1, beta1, a1, cc1, n);

    // layer 2
    k_gemm<true, 128><<<gb_gemm, 256, 0, stream>>>(bufB, W2, dis, a1, cc1, bufA, n);
    k_agg<128><<<gb_agg, 256, 0, stream>>>(bufA, offs, csr, dis, b2, bufB, n);
    k_stats<<<gb_n, 256, 0, stream>>>(bufB, sum2, sq2, n);
    k_bnparams<<<1, 128, 0, stream>>>(sum2, sq2, gamma2, beta2, a2, cc2, n);

    // layer 3 (no BN/ReLU after)
    k_gemm<true, 64><<<gb_gemm, 256, 0, stream>>>(bufB, W3, dis, a2, cc2, bufA, n);
    k_agg<64><<<gb_agg, 256, 0, stream>>>(bufA, offs, csr, dis, b3, out, n);
}

// Round 5
// 372.368 us; speedup vs baseline: 1.8863x; 1.0458x over previous
//
#include <hip/hip_runtime.h>
#include <hip/hip_bf16.h>

// GCN: 3 layers, N=50000 nodes, E=600000 edges, feats 128->128->128->64,
// BatchNorm+ReLU between layers. norm = dis[src]*dis[dst] factorized out.
// GEMM outputs (the ~13x-gathered buffers) stored bf16; everything else fp32.

#define NCHUNK 1024

static __device__ __forceinline__ float4 ld4(const float* p) {
    return *reinterpret_cast<const float4*>(p);
}

// pack two fp32 -> bf16x2 (RNE), memory order lo,hi
static __device__ __forceinline__ unsigned pk2(float lo, float hi) {
    __hip_bfloat162 h = __float22bfloat162_rn(make_float2(lo, hi));
    union { __hip_bfloat162 h2; unsigned u; } c;
    c.h2 = h;
    return c.u;
}
static __device__ __forceinline__ float bf_lo(unsigned u) { return __uint_as_float(u << 16); }
static __device__ __forceinline__ float bf_hi(unsigned u) { return __uint_as_float(u & 0xffff0000u); }

__global__ void k_init(int* __restrict__ cnt, float* __restrict__ stats, int n) {
    int i = blockIdx.x * 256 + threadIdx.x;
    if (i < n) cnt[i] = 0;
    if (i < 512) stats[i] = 0.f;   // sum1[128], sq1[128], sum2[128], sq2[128]
}

__global__ void k_count(const int* __restrict__ dst, int* __restrict__ cnt, int e) {
    int i = blockIdx.x * 256 + threadIdx.x;
    if (i < e) atomicAdd(&cnt[dst[i]], 1);
}

// Stage 1: per-chunk sums of cnt. NCHUNK threads, chunk = contiguous run.
__global__ __launch_bounds__(256) void k_chunksum(const int* __restrict__ cnt,
                                                  int* __restrict__ chunkSum, int n) {
    int t = blockIdx.x * 256 + threadIdx.x;   // 0..NCHUNK-1
    int per = (n + NCHUNK - 1) / NCHUNK;
    int lo = t * per; if (lo > n) lo = n;
    int hi = lo + per; if (hi > n) hi = n;
    int s = 0;
    for (int i = lo; i < hi; ++i) s += cnt[i];
    chunkSum[t] = s;
}

// Stage 2: single-block exclusive scan of chunkSum[NCHUNK] -> chunkBase[NCHUNK].
__global__ __launch_bounds__(1024) void k_chunkscan(const int* __restrict__ chunkSum,
                                                    int* __restrict__ chunkBase) {
    __shared__ int sums[NCHUNK];
    int t = threadIdx.x;
    sums[t] = chunkSum[t];
    __syncthreads();
    for (int off = 1; off < NCHUNK; off <<= 1) {
        int v = (t >= off) ? sums[t - off] : 0;
        __syncthreads();
        sums[t] += v;
        __syncthreads();
    }
    chunkBase[t] = (t == 0) ? 0 : sums[t - 1];
}

// Stage 3: each thread writes offs/cursor/dis for its chunk.
__global__ __launch_bounds__(256) void k_chunkwrite(const int* __restrict__ cnt,
                                                    const int* __restrict__ chunkBase,
                                                    int* __restrict__ offs,
                                                    int* __restrict__ cursor,
                                                    float* __restrict__ dis,
                                                    int n, int e) {
    int t = blockIdx.x * 256 + threadIdx.x;   // 0..NCHUNK-1
    int per = (n + NCHUNK - 1) / NCHUNK;
    int lo = t * per; if (lo > n) lo = n;
    int hi = lo + per; if (hi > n) hi = n;
    int run = chunkBase[t];
    for (int i = lo; i < hi; ++i) {
        offs[i] = run;
        cursor[i] = run;
        int c = cnt[i];
        dis[i] = rsqrtf((float)(c + 1));
        run += c;
    }
    if (t == 0) offs[n] = e;
}

__global__ void k_scatter(const int* __restrict__ src, const int* __restrict__ dst,
                          int* __restrict__ cursor, int* __restrict__ csr, int e) {
    int i = blockIdx.x * 256 + threadIdx.x;
    if (i < e) {
        int p = atomicAdd(&cursor[dst[i]], 1);
        csr[p] = src[i];
    }
}

// out[row][c] = bf16( dis[row] * sum_k in'(row,k) * W[k][c] )
// in'(row,k) = TRANS ? relu(in*ta[k]+tc[k]) : in  (fused BN+ReLU of prev layer)
//
// Block: 64 rows x all NC cols. 256 threads = 4 waves; wave w owns cols
// [w*NC/4, (w+1)*NC/4), lane l owns row l. Input tile staged once in LDS
// [64][129]. W reads are wave-uniform -> scalar loads.
template <bool TRANS, int NC>
__global__ __launch_bounds__(256) void k_gemm(const float* __restrict__ in,
                                              const float* __restrict__ W,
                                              const float* __restrict__ dis,
                                              const float* __restrict__ ta,
                                              const float* __restrict__ tc,
                                              unsigned short* __restrict__ out, int n) {
    constexpr int CGW = NC / 4;           // cols per wave: 32 or 16
    __shared__ float xs[64][129];
    const int tid = threadIdx.x;
    const int row0 = blockIdx.x * 64;

    // stage [64][128] tile: 2048 float4, 8 per thread, coalesced
#pragma unroll
    for (int it = 0; it < 8; ++it) {
        int flat = it * 256 + tid;
        int r = flat >> 5, j = flat & 31;     // j indexes float4 within row
        int grow = row0 + r;
        float4 v = make_float4(0.f, 0.f, 0.f, 0.f);
        if (grow < n) v = ld4(&in[grow * 128 + j * 4]);
        if (TRANS) {
            int f = j * 4;
            float4 A = ld4(&ta[f]);
            float4 C = ld4(&tc[f]);
            v.x = fmaxf(v.x * A.x + C.x, 0.f);
            v.y = fmaxf(v.y * A.y + C.y, 0.f);
            v.z = fmaxf(v.z * A.z + C.z, 0.f);
            v.w = fmaxf(v.w * A.w + C.w, 0.f);
        }
        xs[r][j * 4 + 0] = v.x;
        xs[r][j * 4 + 1] = v.y;
        xs[r][j * 4 + 2] = v.z;
        xs[r][j * 4 + 3] = v.w;
    }
    __syncthreads();

    const int lane = tid & 63;
    const int c0 = __builtin_amdgcn_readfirstlane((tid >> 6) * CGW);

    float acc[CGW];
#pragma unroll
    for (int c = 0; c < CGW; ++c) acc[c] = 0.f;

#pragma unroll 4
    for (int k = 0; k < 128; ++k) {
        float xk = xs[lane][k];
        const float* wr = &W[k * NC + c0];
#pragma unroll
        for (int c = 0; c < CGW; ++c) acc[c] = fmaf(xk, wr[c], acc[c]);
    }

    int row = row0 + lane;
    if (row < n) {
        float d = dis[row];
        unsigned* orow = reinterpret_cast<unsigned*>(out) + ((size_t)row * NC + c0) / 2;
#pragma unroll
        for (int c = 0; c < CGW; c += 8) {
            uint4 o = make_uint4(pk2(acc[c + 0] * d, acc[c + 1] * d),
                                 pk2(acc[c + 2] * d, acc[c + 3] * d),
                                 pk2(acc[c + 4] * d, acc[c + 5] * d),
                                 pk2(acc[c + 6] * d, acc[c + 7] * d));
            *reinterpret_cast<uint4*>(&orow[c / 2]) = o;
        }
    }
}

// One wave per node: out[i] = dis[i] * (hs[i] + sum_{src in(i)} hs[src]) + bias
// hs is bf16. NC=128: 32 lanes x uint2 (4 bf16) per row, 2 edges/wave-step
// (half = lane>>5), 8 edges/iter with 4 independent fp32 accumulators.
// NC=64: same with one uint (2 bf16) per lane.
template <int NC>
__global__ __launch_bounds__(256) void k_agg(const unsigned short* __restrict__ hs,
                                             const int* __restrict__ offs,
                                             const int* __restrict__ csr,
                                             const float* __restrict__ dis,
                                             const float* __restrict__ bias,
                                             float* __restrict__ out, int n) {
    int wave = threadIdx.x >> 6, lane = threadIdx.x & 63;
    int node = blockIdx.x * 4 + wave;
    if (node >= n) return;
    const int e0 = offs[node], e1 = offs[node + 1];
    const int half = lane >> 5, l32 = lane & 31;

    if (NC == 128) {
        const uint2* hp = reinterpret_cast<const uint2*>(hs);   // 32 uint2 per row
        float4 a0 = make_float4(0.f, 0.f, 0.f, 0.f);
        float4 a1 = a0, a2 = a0, a3 = a0;
        if (half == 0) {
            uint2 w = hp[(size_t)node * 32 + l32];              // self-loop
            a0 = make_float4(bf_lo(w.x), bf_hi(w.x), bf_lo(w.y), bf_hi(w.y));
        }
        int e = e0;
        for (; e + 8 <= e1; e += 8) {
            int i0 = csr[e + 0 + half];
            int i1 = csr[e + 2 + half];
            int i2 = csr[e + 4 + half];
            int i3 = csr[e + 6 + half];
            uint2 w0 = hp[(size_t)i0 * 32 + l32];
            uint2 w1 = hp[(size_t)i1 * 32 + l32];
            uint2 w2 = hp[(size_t)i2 * 32 + l32];
            uint2 w3 = hp[(size_t)i3 * 32 + l32];
            a0.x += bf_lo(w0.x); a0.y += bf_hi(w0.x); a0.z += bf_lo(w0.y); a0.w += bf_hi(w0.y);
            a1.x += bf_lo(w1.x); a1.y += bf_hi(w1.x); a1.z += bf_lo(w1.y); a1.w += bf_hi(w1.y);
            a2.x += bf_lo(w2.x); a2.y += bf_hi(w2.x); a2.z += bf_lo(w2.y); a2.w += bf_hi(w2.y);
            a3.x += bf_lo(w3.x); a3.y += bf_hi(w3.x); a3.z += bf_lo(w3.y); a3.w += bf_hi(w3.y);
        }
        for (; e + 2 <= e1; e += 2) {
            int i0 = csr[e + half];
            uint2 w0 = hp[(size_t)i0 * 32 + l32];
            a0.x += bf_lo(w0.x); a0.y += bf_hi(w0.x); a0.z += bf_lo(w0.y); a0.w += bf_hi(w0.y);
        }
        if (e < e1 && half == 0) {
            int i0 = csr[e];
            uint2 w0 = hp[(size_t)i0 * 32 + l32];
            a0.x += bf_lo(w0.x); a0.y += bf_hi(w0.x); a0.z += bf_lo(w0.y); a0.w += bf_hi(w0.y);
        }
        a0.x += a1.x + a2.x + a3.x;
        a0.y += a1.y + a2.y + a3.y;
        a0.z += a1.z + a2.z + a3.z;
        a0.w += a1.w + a2.w + a3.w;
        a0.x += __shfl_down(a0.x, 32);
        a0.y += __shfl_down(a0.y, 32);
        a0.z += __shfl_down(a0.z, 32);
        a0.w += __shfl_down(a0.w, 32);
        if (half == 0) {
            float d = dis[node];
            float4 b = ld4(&bias[l32 * 4]);
            float4 o = make_float4(d * a0.x + b.x, d * a0.y + b.y,
                                   d * a0.z + b.z, d * a0.w + b.w);
            reinterpret_cast<float4*>(out)[(size_t)node * 32 + l32] = o;
        }
    } else {
        const unsigned* hp = reinterpret_cast<const unsigned*>(hs);  // 32 uints per row
        float2 a0 = make_float2(0.f, 0.f);
        float2 a1 = a0, a2 = a0, a3 = a0;
        if (half == 0) {
            unsigned w = hp[(size_t)node * 32 + l32];            // self-loop
            a0 = make_float2(bf_lo(w), bf_hi(w));
        }
        int e = e0;
        for (; e + 8 <= e1; e += 8) {
            int i0 = csr[e + 0 + half];
            int i1 = csr[e + 2 + half];
            int i2 = csr[e + 4 + half];
            int i3 = csr[e + 6 + half];
            unsigned w0 = hp[(size_t)i0 * 32 + l32];
            unsigned w1 = hp[(size_t)i1 * 32 + l32];
            unsigned w2 = hp[(size_t)i2 * 32 + l32];
            unsigned w3 = hp[(size_t)i3 * 32 + l32];
            a0.x += bf_lo(w0); a0.y += bf_hi(w0);
            a1.x += bf_lo(w1); a1.y += bf_hi(w1);
            a2.x += bf_lo(w2); a2.y += bf_hi(w2);
            a3.x += bf_lo(w3); a3.y += bf_hi(w3);
        }
        for (; e + 2 <= e1; e += 2) {
            int i0 = csr[e + half];
            unsigned w0 = hp[(size_t)i0 * 32 + l32];
            a0.x += bf_lo(w0); a0.y += bf_hi(w0);
        }
        if (e < e1 && half == 0) {
            int i0 = csr[e];
            unsigned w0 = hp[(size_t)i0 * 32 + l32];
            a0.x += bf_lo(w0); a0.y += bf_hi(w0);
        }
        a0.x += a1.x + a2.x + a3.x;
        a0.y += a1.y + a2.y + a3.y;
        a0.x += __shfl_down(a0.x, 32);
        a0.y += __shfl_down(a0.y, 32);
        if (half == 0) {
            float d = dis[node];
            float2 o = make_float2(d * a0.x + bias[l32 * 2],
                                   d * a0.y + bias[l32 * 2 + 1]);
            reinterpret_cast<float2*>(out)[(size_t)node * 32 + l32] = o;
        }
    }
}

// Column sums / sumsq over rows (for BN stats). Block handles 256 rows.
__global__ __launch_bounds__(256) void k_stats(const float* __restrict__ h,
                                               float* __restrict__ sum,
                                               float* __restrict__ sumsq, int n) {
    __shared__ float ls[128], ls2[128];
    int c = threadIdx.x & 127, half = threadIdx.x >> 7;
    int r0 = blockIdx.x * 256;
    int rend = r0 + 256; if (rend > n) rend = n;
    float s = 0.f, s2 = 0.f;
    for (int r = r0 + half; r < rend; r += 2) {
        float v = h[r * 128 + c];
        s += v;
        s2 += v * v;
    }
    if (half == 1) { ls[c] = s; ls2[c] = s2; }
    __syncthreads();
    if (half == 0) {
        s += ls[c];
        s2 += ls2[c];
        atomicAdd(&sum[c], s);
        atomicAdd(&sumsq[c], s2);
    }
}

__global__ void k_bnparams(const float* __restrict__ sum, const float* __restrict__ sumsq,
                           const float* __restrict__ gamma, const float* __restrict__ beta,
                           float* __restrict__ a, float* __restrict__ cc, int n) {
    int c = threadIdx.x;
    if (c < 128) {
        float inv_n = 1.0f / (float)n;
        float mean = sum[c] * inv_n;
        float var = sumsq[c] * inv_n - mean * mean;
        float sc = gamma[c] * rsqrtf(var + 1e-5f);
        a[c] = sc;
        cc[c] = beta[c] - mean * sc;
    }
}

extern "C" void kernel_launch(void* const* d_in, const int* in_sizes, int n_in,
                              void* d_out, int out_size, void* d_ws, size_t ws_size,
                              hipStream_t stream) {
    const float* x      = (const float*)d_in[0];
    const int*   ei     = (const int*)d_in[1];     // [2,E] row-major: src then dst
    const float* W1     = (const float*)d_in[2];
    const float* b1     = (const float*)d_in[3];
    const float* gamma1 = (const float*)d_in[4];
    const float* beta1  = (const float*)d_in[5];
    const float* W2     = (const float*)d_in[6];
    const float* b2     = (const float*)d_in[7];
    const float* gamma2 = (const float*)d_in[8];
    const float* beta2  = (const float*)d_in[9];
    const float* W3     = (const float*)d_in[10];
    const float* b3     = (const float*)d_in[11];
    float* out = (float*)d_out;

    const int n = in_sizes[0] / 128;       // 50000
    const int e = in_sizes[1] / 2;         // 600000
    const int* esrc = ei;
    const int* edst = ei + e;

    // workspace layout (256B aligned chunks)
    char* p = (char*)d_ws;
    auto alloc = [&](size_t bytes) {
        void* r = p;
        p += (bytes + 255) & ~size_t(255);
        return r;
    };
    unsigned short* hbf = (unsigned short*)alloc(sizeof(unsigned short) * (size_t)n * 128);
    float* bufB   = (float*)alloc(sizeof(float) * (size_t)n * 128);
    int*   cnt    = (int*)alloc(sizeof(int) * n);
    int*   offs   = (int*)alloc(sizeof(int) * (n + 1));
    int*   cursor = (int*)alloc(sizeof(int) * n);
    int*   csr    = (int*)alloc(sizeof(int) * e);
    float* dis    = (float*)alloc(sizeof(float) * n);
    float* stats  = (float*)alloc(sizeof(float) * 512);  // sum1,sq1,sum2,sq2
    float* bn     = (float*)alloc(sizeof(float) * 512);  // a1,cc1,a2,cc2
    int*   chunkSum  = (int*)alloc(sizeof(int) * NCHUNK);
    int*   chunkBase = (int*)alloc(sizeof(int) * NCHUNK);
    float* sum1 = stats, *sq1 = stats + 128, *sum2 = stats + 256, *sq2 = stats + 384;
    float* a1 = bn, *cc1 = bn + 128, *a2 = bn + 256, *cc2 = bn + 384;

    int gb_n  = (n + 255) / 256;
    int gb_e  = (e + 255) / 256;
    int gb_gemm = (n + 63) / 64;
    int gb_agg = (n + 3) / 4;

    // graph preprocessing (shared by all 3 layers)
    k_init<<<gb_n, 256, 0, stream>>>(cnt, stats, n);
    k_count<<<gb_e, 256, 0, stream>>>(edst, cnt, e);
    k_chunksum<<<NCHUNK / 256, 256, 0, stream>>>(cnt, chunkSum, n);
    k_chunkscan<<<1, NCHUNK, 0, stream>>>(chunkSum, chunkBase);
    k_chunkwrite<<<NCHUNK / 256, 256, 0, stream>>>(cnt, chunkBase, offs, cursor, dis, n, e);
    k_scatter<<<gb_e, 256, 0, stream>>>(esrc, edst, cursor, csr, e);

    // layer 1
    k_gemm<false, 128><<<gb_gemm, 256, 0, stream>>>(x, W1, dis, nullptr, nullptr, hbf, n);
    k_agg<128><<<gb_agg, 256, 0, stream>>>(hbf, offs, csr, dis, b1, bufB, n);
    k_stats<<<gb_n, 256, 0, stream>>>(bufB, sum1, sq1, n);
    k_bnparams<<<1, 128, 0, stream>>>(sum1, sq1, gamma1, beta1, a1, cc1, n);

    // layer 2
    k_gemm<true, 128><<<gb_gemm, 256, 0, stream>>>(bufB, W2, dis, a1, cc1, hbf, n);
    k_agg<128><<<gb_agg, 256, 0, stream>>>(hbf, offs, csr, dis, b2, bufB, n);
    k_stats<<<gb_n, 256, 0, stream>>>(bufB, sum2, sq2, n);
    k_bnparams<<<1, 128, 0, stream>>>(sum2, sq2, gamma2, beta2, a2, cc2, n);

    // layer 3 (no BN/ReLU after)
    k_gemm<true, 64><<<gb_gemm, 256, 0, stream>>>(bufB, W3, dis, a2, cc2, hbf, n);
    k_agg<64><<<gb_agg, 256, 0, stream>>>(hbf, offs, csr, dis, b3, out, n);
}

// Round 6
// 305.901 us; speedup vs baseline: 2.2961x; 1.2173x over previous
//
#include <hip/hip_runtime.h>
#include <hip/hip_bf16.h>

// GCN: 3 layers, N=50000 nodes, E=600000 edges, feats 128->128->128->64,
// BatchNorm+ReLU between layers. norm = dis[src]*dis[dst] factorized out.
// GEMMs on MFMA bf16 (fp32 accum); gathered buffers bf16; rest fp32.

#define NCHUNK 1024

typedef short bf16x8 __attribute__((ext_vector_type(8)));
typedef float f32x4 __attribute__((ext_vector_type(4)));

union FragU { uint4 u; bf16x8 f; };

static __device__ __forceinline__ float4 ld4(const float* p) {
    return *reinterpret_cast<const float4*>(p);
}

// pack two fp32 -> bf16x2 (RNE), memory order lo,hi
static __device__ __forceinline__ unsigned pk2(float lo, float hi) {
    __hip_bfloat162 h = __float22bfloat162_rn(make_float2(lo, hi));
    union { __hip_bfloat162 h2; unsigned u; } c;
    c.h2 = h;
    return c.u;
}
static __device__ __forceinline__ unsigned short bf1(float v) {
    return (unsigned short)(pk2(v, 0.f) & 0xffffu);
}
static __device__ __forceinline__ float bf_lo(unsigned u) { return __uint_as_float(u << 16); }
static __device__ __forceinline__ float bf_hi(unsigned u) { return __uint_as_float(u & 0xffff0000u); }

__global__ void k_init(int* __restrict__ cnt, float* __restrict__ stats, int n) {
    int i = blockIdx.x * 256 + threadIdx.x;
    if (i < n) cnt[i] = 0;
    if (i < 512) stats[i] = 0.f;   // sum1[128], sq1[128], sum2[128], sq2[128]
}

__global__ void k_count(const int* __restrict__ dst, int* __restrict__ cnt, int e) {
    int i = blockIdx.x * 256 + threadIdx.x;
    if (i < e) atomicAdd(&cnt[dst[i]], 1);
}

// Stage 1: per-chunk sums of cnt. NCHUNK threads, chunk = contiguous run.
__global__ __launch_bounds__(256) void k_chunksum(const int* __restrict__ cnt,
                                                  int* __restrict__ chunkSum, int n) {
    int t = blockIdx.x * 256 + threadIdx.x;   // 0..NCHUNK-1
    int per = (n + NCHUNK - 1) / NCHUNK;
    int lo = t * per; if (lo > n) lo = n;
    int hi = lo + per; if (hi > n) hi = n;
    int s = 0;
    for (int i = lo; i < hi; ++i) s += cnt[i];
    chunkSum[t] = s;
}

// Stage 2: single-block exclusive scan of chunkSum[NCHUNK] -> chunkBase[NCHUNK].
__global__ __launch_bounds__(1024) void k_chunkscan(const int* __restrict__ chunkSum,
                                                    int* __restrict__ chunkBase) {
    __shared__ int sums[NCHUNK];
    int t = threadIdx.x;
    sums[t] = chunkSum[t];
    __syncthreads();
    for (int off = 1; off < NCHUNK; off <<= 1) {
        int v = (t >= off) ? sums[t - off] : 0;
        __syncthreads();
        sums[t] += v;
        __syncthreads();
    }
    chunkBase[t] = (t == 0) ? 0 : sums[t - 1];
}

// Stage 3: each thread writes offs/cursor/dis for its chunk.
__global__ __launch_bounds__(256) void k_chunkwrite(const int* __restrict__ cnt,
                                                    const int* __restrict__ chunkBase,
                                                    int* __restrict__ offs,
                                                    int* __restrict__ cursor,
                                                    float* __restrict__ dis,
                                                    int n, int e) {
    int t = blockIdx.x * 256 + threadIdx.x;   // 0..NCHUNK-1
    int per = (n + NCHUNK - 1) / NCHUNK;
    int lo = t * per; if (lo > n) lo = n;
    int hi = lo + per; if (hi > n) hi = n;
    int run = chunkBase[t];
    for (int i = lo; i < hi; ++i) {
        offs[i] = run;
        cursor[i] = run;
        int c = cnt[i];
        dis[i] = rsqrtf((float)(c + 1));
        run += c;
    }
    if (t == 0) offs[n] = e;
}

__global__ void k_scatter(const int* __restrict__ src, const int* __restrict__ dst,
                          int* __restrict__ cursor, int* __restrict__ csr, int e) {
    int i = blockIdx.x * 256 + threadIdx.x;
    if (i < e) {
        int p = atomicAdd(&cursor[dst[i]], 1);
        csr[p] = src[i];
    }
}

// Pre-fragment W into MFMA B-operand order (bf16).
// Frag f = t*4+kk (t = 16-col tile, kk = 32-k step); lane l holds
// B[k = kk*32+(l>>4)*8 + j][col = t*16+(l&15)], j=0..7 contiguous.
template <int NC>
__global__ __launch_bounds__(64) void k_wprep(const float* __restrict__ W,
                                              unsigned short* __restrict__ Wf) {
    int blk = blockIdx.x;          // t*4+kk
    int kk = blk & 3;
    int l = threadIdx.x;
    int col = (blk >> 2) * 16 + (l & 15);
    int k0 = kk * 32 + (l >> 4) * 8;
    unsigned short* dst = &Wf[((size_t)blk * 64 + l) * 8];
#pragma unroll
    for (int j = 0; j < 8; ++j)
        dst[j] = bf1(W[(size_t)(k0 + j) * NC + col]);
}

// out[row][col] = bf16( dis[row] * sum_k in'(row,k) * W[k][col] )
// in'(row,k) = TRANS ? relu(in*ta[k]+tc[k]) : in  (fused BN+ReLU of prev layer)
//
// MFMA 16x16x32 bf16. Block: 32 rows x NC cols, 256 threads = 4 waves.
// Wave w: rows (w>>1)*16..+16, col-half (w&1)*NC/2. A staged bf16 in LDS
// with XOR swizzle byte^=(row&7)<<4 (256B rows -> frag read else 16-way
// bank conflict, G4). B read from pre-fragmented Wf (global, L2-resident).
template <bool TRANS, int NC>
__global__ __launch_bounds__(256) void k_gemm(const float* __restrict__ in,
                                              const uint4* __restrict__ Wf,
                                              const float* __restrict__ dis,
                                              const float* __restrict__ ta,
                                              const float* __restrict__ tc,
                                              unsigned short* __restrict__ out, int n) {
    constexpr int TPW = NC / 32;          // 16-col tiles per wave: 4 or 2
    __shared__ unsigned short xs[32 * 128];
    const int tid = threadIdx.x;
    const int row0 = blockIdx.x * 32;

    // stage 32x128 fp32 -> bf16 LDS (swizzled), 4 float4 per thread
#pragma unroll
    for (int it = 0; it < 4; ++it) {
        int flat = it * 256 + tid;
        int r = flat >> 5, j4 = flat & 31;
        int grow = row0 + r;
        float4 v = make_float4(0.f, 0.f, 0.f, 0.f);
        if (grow < n) v = ld4(&in[(size_t)grow * 128 + j4 * 4]);
        if (TRANS) {
            int f = j4 * 4;
            float4 A = ld4(&ta[f]);
            float4 C = ld4(&tc[f]);
            v.x = fmaxf(v.x * A.x + C.x, 0.f);
            v.y = fmaxf(v.y * A.y + C.y, 0.f);
            v.z = fmaxf(v.z * A.z + C.z, 0.f);
            v.w = fmaxf(v.w * A.w + C.w, 0.f);
        }
        int byte = r * 256 + ((j4 * 8) ^ ((r & 7) << 4));
        *reinterpret_cast<uint2*>(reinterpret_cast<char*>(xs) + byte) =
            make_uint2(pk2(v.x, v.y), pk2(v.z, v.w));
    }
    __syncthreads();

    const int l = tid & 63, w = tid >> 6;
    const int l15 = l & 15, g = l >> 4;
    const int rhalf = (w >> 1) * 16;          // LDS row offset: 0 or 16
    const int tbase = (w & 1) * TPW;          // col-tile offset

    f32x4 acc[TPW];
#pragma unroll
    for (int t = 0; t < TPW; ++t) acc[t] = (f32x4){0.f, 0.f, 0.f, 0.f};

    const int arow = rhalf + l15;
    const char* xb = reinterpret_cast<const char*>(xs) + arow * 256;
    const int aswz = (arow & 7) << 4;

#pragma unroll
    for (int kk = 0; kk < 4; ++kk) {
        FragU a;
        a.u = *reinterpret_cast<const uint4*>(xb + ((kk * 64 + g * 16) ^ aswz));
#pragma unroll
        for (int t = 0; t < TPW; ++t) {
            FragU b;
            b.u = Wf[(size_t)((tbase + t) * 4 + kk) * 64 + l];
            acc[t] = __builtin_amdgcn_mfma_f32_16x16x32_bf16(a.f, b.f, acc[t], 0, 0, 0);
        }
    }

    // epilogue: D[row = g*4+r][col = l15] per tile (m89-verified C/D layout)
    const int rbase = row0 + rhalf + g * 4;
    float dv[4];
#pragma unroll
    for (int r = 0; r < 4; ++r) {
        int rr = rbase + r;
        dv[r] = (rr < n) ? dis[rr] : 0.f;
    }
#pragma unroll
    for (int t = 0; t < TPW; ++t) {
        int col = (tbase + t) * 16 + l15;
#pragma unroll
        for (int r = 0; r < 4; ++r) {
            int rr = rbase + r;
            if (rr < n) out[(size_t)rr * NC + col] = bf1(acc[t][r] * dv[r]);
        }
    }
}

// One wave per node: out[i] = dis[i] * (hs[i] + sum_{src in(i)} hs[src]) + bias
// hs is bf16. NC=128: 32 lanes x uint2 (4 bf16) per row, 2 edges/wave-step
// (half = lane>>5), 8 edges/iter with 4 independent fp32 accumulators.
// NC=64: same with one uint (2 bf16) per lane.
template <int NC>
__global__ __launch_bounds__(256) void k_agg(const unsigned short* __restrict__ hs,
                                             const int* __restrict__ offs,
                                             const int* __restrict__ csr,
                                             const float* __restrict__ dis,
                                             const float* __restrict__ bias,
                                             float* __restrict__ out, int n) {
    int wave = threadIdx.x >> 6, lane = threadIdx.x & 63;
    int node = blockIdx.x * 4 + wave;
    if (node >= n) return;
    const int e0 = offs[node], e1 = offs[node + 1];
    const int half = lane >> 5, l32 = lane & 31;

    if (NC == 128) {
        const uint2* hp = reinterpret_cast<const uint2*>(hs);   // 32 uint2 per row
        float4 a0 = make_float4(0.f, 0.f, 0.f, 0.f);
        float4 a1 = a0, a2 = a0, a3 = a0;
        if (half == 0) {
            uint2 w = hp[(size_t)node * 32 + l32];              // self-loop
            a0 = make_float4(bf_lo(w.x), bf_hi(w.x), bf_lo(w.y), bf_hi(w.y));
        }
        int e = e0;
        for (; e + 8 <= e1; e += 8) {
            int i0 = csr[e + 0 + half];
            int i1 = csr[e + 2 + half];
            int i2 = csr[e + 4 + half];
            int i3 = csr[e + 6 + half];
            uint2 w0 = hp[(size_t)i0 * 32 + l32];
            uint2 w1 = hp[(size_t)i1 * 32 + l32];
            uint2 w2 = hp[(size_t)i2 * 32 + l32];
            uint2 w3 = hp[(size_t)i3 * 32 + l32];
            a0.x += bf_lo(w0.x); a0.y += bf_hi(w0.x); a0.z += bf_lo(w0.y); a0.w += bf_hi(w0.y);
            a1.x += bf_lo(w1.x); a1.y += bf_hi(w1.x); a1.z += bf_lo(w1.y); a1.w += bf_hi(w1.y);
            a2.x += bf_lo(w2.x); a2.y += bf_hi(w2.x); a2.z += bf_lo(w2.y); a2.w += bf_hi(w2.y);
            a3.x += bf_lo(w3.x); a3.y += bf_hi(w3.x); a3.z += bf_lo(w3.y); a3.w += bf_hi(w3.y);
        }
        for (; e + 2 <= e1; e += 2) {
            int i0 = csr[e + half];
            uint2 w0 = hp[(size_t)i0 * 32 + l32];
            a0.x += bf_lo(w0.x); a0.y += bf_hi(w0.x); a0.z += bf_lo(w0.y); a0.w += bf_hi(w0.y);
        }
        if (e < e1 && half == 0) {
            int i0 = csr[e];
            uint2 w0 = hp[(size_t)i0 * 32 + l32];
            a0.x += bf_lo(w0.x); a0.y += bf_hi(w0.x); a0.z += bf_lo(w0.y); a0.w += bf_hi(w0.y);
        }
        a0.x += a1.x + a2.x + a3.x;
        a0.y += a1.y + a2.y + a3.y;
        a0.z += a1.z + a2.z + a3.z;
        a0.w += a1.w + a2.w + a3.w;
        a0.x += __shfl_down(a0.x, 32);
        a0.y += __shfl_down(a0.y, 32);
        a0.z += __shfl_down(a0.z, 32);
        a0.w += __shfl_down(a0.w, 32);
        if (half == 0) {
            float d = dis[node];
            float4 b = ld4(&bias[l32 * 4]);
            float4 o = make_float4(d * a0.x + b.x, d * a0.y + b.y,
                                   d * a0.z + b.z, d * a0.w + b.w);
            reinterpret_cast<float4*>(out)[(size_t)node * 32 + l32] = o;
        }
    } else {
        const unsigned* hp = reinterpret_cast<const unsigned*>(hs);  // 32 uints per row
        float2 a0 = make_float2(0.f, 0.f);
        float2 a1 = a0, a2 = a0, a3 = a0;
        if (half == 0) {
            unsigned w = hp[(size_t)node * 32 + l32];            // self-loop
            a0 = make_float2(bf_lo(w), bf_hi(w));
        }
        int e = e0;
        for (; e + 8 <= e1; e += 8) {
            int i0 = csr[e + 0 + half];
            int i1 = csr[e + 2 + half];
            int i2 = csr[e + 4 + half];
            int i3 = csr[e + 6 + half];
            unsigned w0 = hp[(size_t)i0 * 32 + l32];
            unsigned w1 = hp[(size_t)i1 * 32 + l32];
            unsigned w2 = hp[(size_t)i2 * 32 + l32];
            unsigned w3 = hp[(size_t)i3 * 32 + l32];
            a0.x += bf_lo(w0); a0.y += bf_hi(w0);
            a1.x += bf_lo(w1); a1.y += bf_hi(w1);
            a2.x += bf_lo(w2); a2.y += bf_hi(w2);
            a3.x += bf_lo(w3); a3.y += bf_hi(w3);
        }
        for (; e + 2 <= e1; e += 2) {
            int i0 = csr[e + half];
            unsigned w0 = hp[(size_t)i0 * 32 + l32];
            a0.x += bf_lo(w0); a0.y += bf_hi(w0);
        }
        if (e < e1 && half == 0) {
            int i0 = csr[e];
            unsigned w0 = hp[(size_t)i0 * 32 + l32];
            a0.x += bf_lo(w0); a0.y += bf_hi(w0);
        }
        a0.x += a1.x + a2.x + a3.x;
        a0.y += a1.y + a2.y + a3.y;
        a0.x += __shfl_down(a0.x, 32);
        a0.y += __shfl_down(a0.y, 32);
        if (half == 0) {
            float d = dis[node];
            float2 o = make_float2(d * a0.x + bias[l32 * 2],
                                   d * a0.y + bias[l32 * 2 + 1]);
            reinterpret_cast<float2*>(out)[(size_t)node * 32 + l32] = o;
        }
    }
}

// Column sums / sumsq over rows (for BN stats). Block handles 256 rows.
__global__ __launch_bounds__(256) void k_stats(const float* __restrict__ h,
                                               float* __restrict__ sum,
                                               float* __restrict__ sumsq, int n) {
    __shared__ float ls[128], ls2[128];
    int c = threadIdx.x & 127, half = threadIdx.x >> 7;
    int r0 = blockIdx.x * 256;
    int rend = r0 + 256; if (rend > n) rend = n;
    float s = 0.f, s2 = 0.f;
    for (int r = r0 + half; r < rend; r += 2) {
        float v = h[r * 128 + c];
        s += v;
        s2 += v * v;
    }
    if (half == 1) { ls[c] = s; ls2[c] = s2; }
    __syncthreads();
    if (half == 0) {
        s += ls[c];
        s2 += ls2[c];
        atomicAdd(&sum[c], s);
        atomicAdd(&sumsq[c], s2);
    }
}

__global__ void k_bnparams(const float* __restrict__ sum, const float* __restrict__ sumsq,
                           const float* __restrict__ gamma, const float* __restrict__ beta,
                           float* __restrict__ a, float* __restrict__ cc, int n) {
    int c = threadIdx.x;
    if (c < 128) {
        float inv_n = 1.0f / (float)n;
        float mean = sum[c] * inv_n;
        float var = sumsq[c] * inv_n - mean * mean;
        float sc = gamma[c] * rsqrtf(var + 1e-5f);
        a[c] = sc;
        cc[c] = beta[c] - mean * sc;
    }
}

extern "C" void kernel_launch(void* const* d_in, const int* in_sizes, int n_in,
                              void* d_out, int out_size, void* d_ws, size_t ws_size,
                              hipStream_t stream) {
    const float* x      = (const float*)d_in[0];
    const int*   ei     = (const int*)d_in[1];     // [2,E] row-major: src then dst
    const float* W1     = (const float*)d_in[2];
    const float* b1     = (const float*)d_in[3];
    const float* gamma1 = (const float*)d_in[4];
    const float* beta1  = (const float*)d_in[5];
    const float* W2     = (const float*)d_in[6];
    const float* b2     = (const float*)d_in[7];
    const float* gamma2 = (const float*)d_in[8];
    const float* beta2  = (const float*)d_in[9];
    const float* W3     = (const float*)d_in[10];
    const float* b3     = (const float*)d_in[11];
    float* out = (float*)d_out;

    const int n = in_sizes[0] / 128;       // 50000
    const int e = in_sizes[1] / 2;         // 600000
    const int* esrc = ei;
    const int* edst = ei + e;

    // workspace layout (256B aligned chunks)
    char* p = (char*)d_ws;
    auto alloc = [&](size_t bytes) {
        void* r = p;
        p += (bytes + 255) & ~size_t(255);
        return r;
    };
    unsigned short* hbf = (unsigned short*)alloc(sizeof(unsigned short) * (size_t)n * 128);
    float* bufB   = (float*)alloc(sizeof(float) * (size_t)n * 128);
    int*   cnt    = (int*)alloc(sizeof(int) * n);
    int*   offs   = (int*)alloc(sizeof(int) * (n + 1));
    int*   cursor = (int*)alloc(sizeof(int) * n);
    int*   csr    = (int*)alloc(sizeof(int) * e);
    float* dis    = (float*)alloc(sizeof(float) * n);
    float* stats  = (float*)alloc(sizeof(float) * 512);  // sum1,sq1,sum2,sq2
    float* bn     = (float*)alloc(sizeof(float) * 512);  // a1,cc1,a2,cc2
    int*   chunkSum  = (int*)alloc(sizeof(int) * NCHUNK);
    int*   chunkBase = (int*)alloc(sizeof(int) * NCHUNK);
    unsigned short* wf1 = (unsigned short*)alloc(sizeof(unsigned short) * 32 * 64 * 8);
    unsigned short* wf2 = (unsigned short*)alloc(sizeof(unsigned short) * 32 * 64 * 8);
    unsigned short* wf3 = (unsigned short*)alloc(sizeof(unsigned short) * 16 * 64 * 8);
    float* sum1 = stats, *sq1 = stats + 128, *sum2 = stats + 256, *sq2 = stats + 384;
    float* a1 = bn, *cc1 = bn + 128, *a2 = bn + 256, *cc2 = bn + 384;

    int gb_n  = (n + 255) / 256;
    int gb_e  = (e + 255) / 256;
    int gb_gemm = (n + 31) / 32;
    int gb_agg = (n + 3) / 4;

    // graph preprocessing (shared by all 3 layers) + W fragment prep
    k_init<<<gb_n, 256, 0, stream>>>(cnt, stats, n);
    k_count<<<gb_e, 256, 0, stream>>>(edst, cnt, e);
    k_wprep<128><<<32, 64, 0, stream>>>(W1, wf1);
    k_wprep<128><<<32, 64, 0, stream>>>(W2, wf2);
    k_wprep<64><<<16, 64, 0, stream>>>(W3, wf3);
    k_chunksum<<<NCHUNK / 256, 256, 0, stream>>>(cnt, chunkSum, n);
    k_chunkscan<<<1, NCHUNK, 0, stream>>>(chunkSum, chunkBase);
    k_chunkwrite<<<NCHUNK / 256, 256, 0, stream>>>(cnt, chunkBase, offs, cursor, dis, n, e);
    k_scatter<<<gb_e, 256, 0, stream>>>(esrc, edst, cursor, csr, e);

    // layer 1
    k_gemm<false, 128><<<gb_gemm, 256, 0, stream>>>(x, (const uint4*)wf1, dis, nullptr, nullptr, hbf, n);
    k_agg<128><<<gb_agg, 256, 0, stream>>>(hbf, offs, csr, dis, b1, bufB, n);
    k_stats<<<gb_n, 256, 0, stream>>>(bufB, sum1, sq1, n);
    k_bnparams<<<1, 128, 0, stream>>>(sum1, sq1, gamma1, beta1, a1, cc1, n);

    // layer 2
    k_gemm<true, 128><<<gb_gemm, 256, 0, stream>>>(bufB, (const uint4*)wf2, dis, a1, cc1, hbf, n);
    k_agg<128><<<gb_agg, 256, 0, stream>>>(hbf, offs, csr, dis, b2, bufB, n);
    k_stats<<<gb_n, 256, 0, stream>>>(bufB, sum2, sq2, n);
    k_bnparams<<<1, 128, 0, stream>>>(sum2, sq2, gamma2, beta2, a2, cc2, n);

    // layer 3 (no BN/ReLU after)
    k_gemm<true, 64><<<gb_gemm, 256, 0, stream>>>(bufB, (const uint4*)wf3, dis, a2, cc2, hbf, n);
    k_agg<64><<<gb_agg, 256, 0, stream>>>(hbf, offs, csr, dis, b3, out, n);
}

// Round 7
// 248.880 us; speedup vs baseline: 2.8222x; 1.2291x over previous
//
#include <hip/hip_runtime.h>
#include <hip/hip_bf16.h>

// GCN: 3 layers, N=50000 nodes, E=600000 edges, feats 128->128->128->64,
// BatchNorm+ReLU between layers. norm = dis[src]*dis[dst] factorized out.
// GEMMs on MFMA bf16 (fp32 accum); all intermediate buffers bf16; BN stats
// fused into k_agg epilogue (64-slot atomic partials).

#define NCHUNK 1024
#define NSLOT 64

typedef short bf16x8 __attribute__((ext_vector_type(8)));
typedef float f32x4 __attribute__((ext_vector_type(4)));

union FragU { uint4 u; bf16x8 f; };

static __device__ __forceinline__ float4 ld4(const float* p) {
    return *reinterpret_cast<const float4*>(p);
}

// pack two fp32 -> bf16x2 (RNE), memory order lo,hi
static __device__ __forceinline__ unsigned pk2(float lo, float hi) {
    __hip_bfloat162 h = __float22bfloat162_rn(make_float2(lo, hi));
    union { __hip_bfloat162 h2; unsigned u; } c;
    c.h2 = h;
    return c.u;
}
static __device__ __forceinline__ unsigned short bf1(float v) {
    return (unsigned short)(pk2(v, 0.f) & 0xffffu);
}
static __device__ __forceinline__ float bf_lo(unsigned u) { return __uint_as_float(u << 16); }
static __device__ __forceinline__ float bf_hi(unsigned u) { return __uint_as_float(u & 0xffff0000u); }

__global__ void k_init(int* __restrict__ cnt, float* __restrict__ stats, int n) {
    int i = blockIdx.x * 256 + threadIdx.x;
    if (i < n) cnt[i] = 0;
    if (i < 4 * NSLOT * 128) stats[i] = 0.f;   // ssum1, ssq1, ssum2, ssq2
}

__global__ void k_count(const int* __restrict__ dst, int* __restrict__ cnt, int e) {
    int i = blockIdx.x * 256 + threadIdx.x;
    if (i < e) atomicAdd(&cnt[dst[i]], 1);
}

// Stage 1: per-chunk sums of cnt. NCHUNK threads, chunk = contiguous run.
__global__ __launch_bounds__(256) void k_chunksum(const int* __restrict__ cnt,
                                                  int* __restrict__ chunkSum, int n) {
    int t = blockIdx.x * 256 + threadIdx.x;   // 0..NCHUNK-1
    int per = (n + NCHUNK - 1) / NCHUNK;
    int lo = t * per; if (lo > n) lo = n;
    int hi = lo + per; if (hi > n) hi = n;
    int s = 0;
    for (int i = lo; i < hi; ++i) s += cnt[i];
    chunkSum[t] = s;
}

// Stage 2: single-block exclusive scan of chunkSum[NCHUNK] -> chunkBase[NCHUNK].
__global__ __launch_bounds__(1024) void k_chunkscan(const int* __restrict__ chunkSum,
                                                    int* __restrict__ chunkBase) {
    __shared__ int sums[NCHUNK];
    int t = threadIdx.x;
    sums[t] = chunkSum[t];
    __syncthreads();
    for (int off = 1; off < NCHUNK; off <<= 1) {
        int v = (t >= off) ? sums[t - off] : 0;
        __syncthreads();
        sums[t] += v;
        __syncthreads();
    }
    chunkBase[t] = (t == 0) ? 0 : sums[t - 1];
}

// Stage 3: each thread writes offs/cursor/dis for its chunk.
__global__ __launch_bounds__(256) void k_chunkwrite(const int* __restrict__ cnt,
                                                    const int* __restrict__ chunkBase,
                                                    int* __restrict__ offs,
                                                    int* __restrict__ cursor,
                                                    float* __restrict__ dis,
                                                    int n, int e) {
    int t = blockIdx.x * 256 + threadIdx.x;   // 0..NCHUNK-1
    int per = (n + NCHUNK - 1) / NCHUNK;
    int lo = t * per; if (lo > n) lo = n;
    int hi = lo + per; if (hi > n) hi = n;
    int run = chunkBase[t];
    for (int i = lo; i < hi; ++i) {
        offs[i] = run;
        cursor[i] = run;
        int c = cnt[i];
        dis[i] = rsqrtf((float)(c + 1));
        run += c;
    }
    if (t == 0) offs[n] = e;
}

__global__ void k_scatter(const int* __restrict__ src, const int* __restrict__ dst,
                          int* __restrict__ cursor, int* __restrict__ csr, int e) {
    int i = blockIdx.x * 256 + threadIdx.x;
    if (i < e) {
        int p = atomicAdd(&cursor[dst[i]], 1);
        csr[p] = src[i];
    }
}

// Pre-fragment W1,W2,W3 into MFMA B-operand order (bf16), one dispatch.
// Frag f = t*4+kk; lane l holds B[k = kk*32+(l>>4)*8+j][col = t*16+(l&15)].
__global__ __launch_bounds__(64) void k_wprep3(const float* __restrict__ W1,
                                               const float* __restrict__ W2,
                                               const float* __restrict__ W3,
                                               unsigned short* __restrict__ wf1,
                                               unsigned short* __restrict__ wf2,
                                               unsigned short* __restrict__ wf3) {
    int b = blockIdx.x;
    const float* W; unsigned short* Wf; int NC; int blk;
    if (b < 32)      { W = W1; Wf = wf1; NC = 128; blk = b; }
    else if (b < 64) { W = W2; Wf = wf2; NC = 128; blk = b - 32; }
    else             { W = W3; Wf = wf3; NC = 64;  blk = b - 64; }
    int kk = blk & 3;
    int l = threadIdx.x;
    int col = (blk >> 2) * 16 + (l & 15);
    int k0 = kk * 32 + (l >> 4) * 8;
    unsigned short* dst = &Wf[((size_t)blk * 64 + l) * 8];
#pragma unroll
    for (int j = 0; j < 8; ++j)
        dst[j] = bf1(W[(size_t)(k0 + j) * NC + col]);
}

// out[row][col] = bf16( dis[row] * sum_k in'(row,k) * W[k][col] )
// in'(row,k) = TRANS ? relu(in*ta[k]+tc[k]) : in.  INBF: input rows are bf16.
//
// MFMA 16x16x32 bf16. Block: 32 rows x NC cols, 256 threads = 4 waves.
// Wave w: rows (w>>1)*16..+16, col-half (w&1)*NC/2. A staged bf16 in LDS
// with XOR swizzle byte^=(row&7)<<4 (G4). B from pre-fragmented Wf.
template <bool TRANS, int NC, bool INBF>
__global__ __launch_bounds__(256) void k_gemm(const void* __restrict__ inv,
                                              const uint4* __restrict__ Wf,
                                              const float* __restrict__ dis,
                                              const float* __restrict__ ta,
                                              const float* __restrict__ tc,
                                              unsigned short* __restrict__ out, int n) {
    constexpr int TPW = NC / 32;          // 16-col tiles per wave: 4 or 2
    __shared__ unsigned short xs[32 * 128];
    const int tid = threadIdx.x;
    const int row0 = blockIdx.x * 32;

    if constexpr (INBF) {
        const unsigned short* in = (const unsigned short*)inv;
#pragma unroll
        for (int it = 0; it < 2; ++it) {
            int flat = it * 256 + tid;
            int r = flat >> 4, j = flat & 15;     // j indexes uint4 (8 bf16)
            int grow = row0 + r;
            uint4 v = make_uint4(0, 0, 0, 0);
            if (grow < n) v = *reinterpret_cast<const uint4*>(&in[(size_t)grow * 128 + j * 8]);
            if (TRANS) {
                int f = j * 8;
                float4 A0 = ld4(&ta[f]), A1 = ld4(&ta[f + 4]);
                float4 C0 = ld4(&tc[f]), C1 = ld4(&tc[f + 4]);
                v.x = pk2(fmaxf(bf_lo(v.x) * A0.x + C0.x, 0.f),
                          fmaxf(bf_hi(v.x) * A0.y + C0.y, 0.f));
                v.y = pk2(fmaxf(bf_lo(v.y) * A0.z + C0.z, 0.f),
                          fmaxf(bf_hi(v.y) * A0.w + C0.w, 0.f));
                v.z = pk2(fmaxf(bf_lo(v.z) * A1.x + C1.x, 0.f),
                          fmaxf(bf_hi(v.z) * A1.y + C1.y, 0.f));
                v.w = pk2(fmaxf(bf_lo(v.w) * A1.z + C1.z, 0.f),
                          fmaxf(bf_hi(v.w) * A1.w + C1.w, 0.f));
            }
            int byte = r * 256 + ((j * 16) ^ ((r & 7) << 4));
            *reinterpret_cast<uint4*>(reinterpret_cast<char*>(xs) + byte) = v;
        }
    } else {
        const float* in = (const float*)inv;
#pragma unroll
        for (int it = 0; it < 4; ++it) {
            int flat = it * 256 + tid;
            int r = flat >> 5, j4 = flat & 31;
            int grow = row0 + r;
            float4 v = make_float4(0.f, 0.f, 0.f, 0.f);
            if (grow < n) v = ld4(&in[(size_t)grow * 128 + j4 * 4]);
            if (TRANS) {
                int f = j4 * 4;
                float4 A = ld4(&ta[f]);
                float4 C = ld4(&tc[f]);
                v.x = fmaxf(v.x * A.x + C.x, 0.f);
                v.y = fmaxf(v.y * A.y + C.y, 0.f);
                v.z = fmaxf(v.z * A.z + C.z, 0.f);
                v.w = fmaxf(v.w * A.w + C.w, 0.f);
            }
            int byte = r * 256 + ((j4 * 8) ^ ((r & 7) << 4));
            *reinterpret_cast<uint2*>(reinterpret_cast<char*>(xs) + byte) =
                make_uint2(pk2(v.x, v.y), pk2(v.z, v.w));
        }
    }
    __syncthreads();

    const int l = tid & 63, w = tid >> 6;
    const int l15 = l & 15, g = l >> 4;
    const int rhalf = (w >> 1) * 16;          // LDS row offset: 0 or 16
    const int tbase = (w & 1) * TPW;          // col-tile offset

    f32x4 acc[TPW];
#pragma unroll
    for (int t = 0; t < TPW; ++t) acc[t] = (f32x4){0.f, 0.f, 0.f, 0.f};

    const int arow = rhalf + l15;
    const char* xb = reinterpret_cast<const char*>(xs) + arow * 256;
    const int aswz = (arow & 7) << 4;

#pragma unroll
    for (int kk = 0; kk < 4; ++kk) {
        FragU a;
        a.u = *reinterpret_cast<const uint4*>(xb + ((kk * 64 + g * 16) ^ aswz));
#pragma unroll
        for (int t = 0; t < TPW; ++t) {
            FragU b;
            b.u = Wf[(size_t)((tbase + t) * 4 + kk) * 64 + l];
            acc[t] = __builtin_amdgcn_mfma_f32_16x16x32_bf16(a.f, b.f, acc[t], 0, 0, 0);
        }
    }

    // epilogue: D[row = g*4+r][col = l15] per tile (m89-verified C/D layout)
    const int rbase = row0 + rhalf + g * 4;
    float dv[4];
#pragma unroll
    for (int r = 0; r < 4; ++r) {
        int rr = rbase + r;
        dv[r] = (rr < n) ? dis[rr] : 0.f;
    }
#pragma unroll
    for (int t = 0; t < TPW; ++t) {
        int col = (tbase + t) * 16 + l15;
#pragma unroll
        for (int r = 0; r < 4; ++r) {
            int rr = rbase + r;
            if (rr < n) out[(size_t)rr * NC + col] = bf1(acc[t][r] * dv[r]);
        }
    }
}

// One wave per node: h[i] = dis[i] * (hs[i] + sum_{src in(i)} hs[src]) + bias.
// hs bf16. NC=128: writes bf16 + fused BN column stats (LDS reduce, 64-slot
// atomic partials). NC=64: writes fp32 to d_out, no stats.
template <int NC, bool STATS>
__global__ __launch_bounds__(256) void k_agg(const unsigned short* __restrict__ hs,
                                             const int* __restrict__ offs,
                                             const int* __restrict__ csr,
                                             const float* __restrict__ dis,
                                             const float* __restrict__ bias,
                                             void* __restrict__ outv,
                                             float* __restrict__ ssum,
                                             float* __restrict__ ssq, int n) {
    int wave = threadIdx.x >> 6, lane = threadIdx.x & 63;
    int node = blockIdx.x * 4 + wave;
    const int half = lane >> 5, l32 = lane & 31;

    if (NC == 128) {
        int e0 = 0, e1 = 0;
        if (node < n) { e0 = offs[node]; e1 = offs[node + 1]; }
        const uint2* hp = reinterpret_cast<const uint2*>(hs);   // 32 uint2 per row
        float4 a0 = make_float4(0.f, 0.f, 0.f, 0.f);
        float4 a1 = a0, a2 = a0, a3 = a0;
        if (half == 0 && node < n) {
            uint2 w = hp[(size_t)node * 32 + l32];              // self-loop
            a0 = make_float4(bf_lo(w.x), bf_hi(w.x), bf_lo(w.y), bf_hi(w.y));
        }
        int e = e0;
        for (; e + 8 <= e1; e += 8) {
            int i0 = csr[e + 0 + half];
            int i1 = csr[e + 2 + half];
            int i2 = csr[e + 4 + half];
            int i3 = csr[e + 6 + half];
            uint2 w0 = hp[(size_t)i0 * 32 + l32];
            uint2 w1 = hp[(size_t)i1 * 32 + l32];
            uint2 w2 = hp[(size_t)i2 * 32 + l32];
            uint2 w3 = hp[(size_t)i3 * 32 + l32];
            a0.x += bf_lo(w0.x); a0.y += bf_hi(w0.x); a0.z += bf_lo(w0.y); a0.w += bf_hi(w0.y);
            a1.x += bf_lo(w1.x); a1.y += bf_hi(w1.x); a1.z += bf_lo(w1.y); a1.w += bf_hi(w1.y);
            a2.x += bf_lo(w2.x); a2.y += bf_hi(w2.x); a2.z += bf_lo(w2.y); a2.w += bf_hi(w2.y);
            a3.x += bf_lo(w3.x); a3.y += bf_hi(w3.x); a3.z += bf_lo(w3.y); a3.w += bf_hi(w3.y);
        }
        for (; e + 2 <= e1; e += 2) {
            int i0 = csr[e + half];
            uint2 w0 = hp[(size_t)i0 * 32 + l32];
            a0.x += bf_lo(w0.x); a0.y += bf_hi(w0.x); a0.z += bf_lo(w0.y); a0.w += bf_hi(w0.y);
        }
        if (e < e1 && half == 0) {
            int i0 = csr[e];
            uint2 w0 = hp[(size_t)i0 * 32 + l32];
            a0.x += bf_lo(w0.x); a0.y += bf_hi(w0.x); a0.z += bf_lo(w0.y); a0.w += bf_hi(w0.y);
        }
        a0.x += a1.x + a2.x + a3.x;
        a0.y += a1.y + a2.y + a3.y;
        a0.z += a1.z + a2.z + a3.z;
        a0.w += a1.w + a2.w + a3.w;
        a0.x += __shfl_down(a0.x, 32);
        a0.y += __shfl_down(a0.y, 32);
        a0.z += __shfl_down(a0.z, 32);
        a0.w += __shfl_down(a0.w, 32);
        float4 oV = make_float4(0.f, 0.f, 0.f, 0.f);
        if (half == 0 && node < n) {
            float d = dis[node];
            float4 b = ld4(&bias[l32 * 4]);
            oV = make_float4(d * a0.x + b.x, d * a0.y + b.y,
                             d * a0.z + b.z, d * a0.w + b.w);
            uint2 w = make_uint2(pk2(oV.x, oV.y), pk2(oV.z, oV.w));
            reinterpret_cast<uint2*>(outv)[(size_t)node * 32 + l32] = w;
        }
        if constexpr (STATS) {
            __shared__ float ls[4][128];
            __shared__ float ls2[4][128];
            if (half == 0) {
                int c = l32 * 4;
                ls[wave][c + 0] = oV.x; ls2[wave][c + 0] = oV.x * oV.x;
                ls[wave][c + 1] = oV.y; ls2[wave][c + 1] = oV.y * oV.y;
                ls[wave][c + 2] = oV.z; ls2[wave][c + 2] = oV.z * oV.z;
                ls[wave][c + 3] = oV.w; ls2[wave][c + 3] = oV.w * oV.w;
            }
            __syncthreads();
            int t = threadIdx.x;
            int slot = (blockIdx.x & (NSLOT - 1)) * 128;
            if (t < 128) {
                float s = ls[0][t] + ls[1][t] + ls[2][t] + ls[3][t];
                atomicAdd(&ssum[slot + t], s);
            } else {
                int c = t - 128;
                float s2 = ls2[0][c] + ls2[1][c] + ls2[2][c] + ls2[3][c];
                atomicAdd(&ssq[slot + c], s2);
            }
        }
    } else {
        if (node >= n) return;
        int e0 = offs[node], e1 = offs[node + 1];
        const unsigned* hp = reinterpret_cast<const unsigned*>(hs);  // 32 uints per row
        float2 a0 = make_float2(0.f, 0.f);
        float2 a1 = a0, a2 = a0, a3 = a0;
        if (half == 0) {
            unsigned w = hp[(size_t)node * 32 + l32];            // self-loop
            a0 = make_float2(bf_lo(w), bf_hi(w));
        }
        int e = e0;
        for (; e + 8 <= e1; e += 8) {
            int i0 = csr[e + 0 + half];
            int i1 = csr[e + 2 + half];
            int i2 = csr[e + 4 + half];
            int i3 = csr[e + 6 + half];
            unsigned w0 = hp[(size_t)i0 * 32 + l32];
            unsigned w1 = hp[(size_t)i1 * 32 + l32];
            unsigned w2 = hp[(size_t)i2 * 32 + l32];
            unsigned w3 = hp[(size_t)i3 * 32 + l32];
            a0.x += bf_lo(w0); a0.y += bf_hi(w0);
            a1.x += bf_lo(w1); a1.y += bf_hi(w1);
            a2.x += bf_lo(w2); a2.y += bf_hi(w2);
            a3.x += bf_lo(w3); a3.y += bf_hi(w3);
        }
        for (; e + 2 <= e1; e += 2) {
            int i0 = csr[e + half];
            unsigned w0 = hp[(size_t)i0 * 32 + l32];
            a0.x += bf_lo(w0); a0.y += bf_hi(w0);
        }
        if (e < e1 && half == 0) {
            int i0 = csr[e];
            unsigned w0 = hp[(size_t)i0 * 32 + l32];
            a0.x += bf_lo(w0); a0.y += bf_hi(w0);
        }
        a0.x += a1.x + a2.x + a3.x;
        a0.y += a1.y + a2.y + a3.y;
        a0.x += __shfl_down(a0.x, 32);
        a0.y += __shfl_down(a0.y, 32);
        if (half == 0) {
            float d = dis[node];
            float2 o = make_float2(d * a0.x + bias[l32 * 2],
                                   d * a0.y + bias[l32 * 2 + 1]);
            reinterpret_cast<float2*>(outv)[(size_t)node * 32 + l32] = o;
        }
    }
}

// Reduce 64-slot partials -> BN affine params a, cc.
__global__ void k_bnparams(const float* __restrict__ ssum, const float* __restrict__ ssq,
                           const float* __restrict__ gamma, const float* __restrict__ beta,
                           float* __restrict__ a, float* __restrict__ cc, int n) {
    int c = threadIdx.x;
    if (c < 128) {
        float s = 0.f, s2 = 0.f;
        for (int k = 0; k < NSLOT; ++k) {
            s += ssum[k * 128 + c];
            s2 += ssq[k * 128 + c];
        }
        float inv_n = 1.0f / (float)n;
        float mean = s * inv_n;
        float var = s2 * inv_n - mean * mean;
        float sc = gamma[c] * rsqrtf(var + 1e-5f);
        a[c] = sc;
        cc[c] = beta[c] - mean * sc;
    }
}

extern "C" void kernel_launch(void* const* d_in, const int* in_sizes, int n_in,
                              void* d_out, int out_size, void* d_ws, size_t ws_size,
                              hipStream_t stream) {
    const float* x      = (const float*)d_in[0];
    const int*   ei     = (const int*)d_in[1];     // [2,E] row-major: src then dst
    const float* W1     = (const float*)d_in[2];
    const float* b1     = (const float*)d_in[3];
    const float* gamma1 = (const float*)d_in[4];
    const float* beta1  = (const float*)d_in[5];
    const float* W2     = (const float*)d_in[6];
    const float* b2     = (const float*)d_in[7];
    const float* gamma2 = (const float*)d_in[8];
    const float* beta2  = (const float*)d_in[9];
    const float* W3     = (const float*)d_in[10];
    const float* b3     = (const float*)d_in[11];
    float* out = (float*)d_out;

    const int n = in_sizes[0] / 128;       // 50000
    const int e = in_sizes[1] / 2;         // 600000
    const int* esrc = ei;
    const int* edst = ei + e;

    // workspace layout (256B aligned chunks)
    char* p = (char*)d_ws;
    auto alloc = [&](size_t bytes) {
        void* r = p;
        p += (bytes + 255) & ~size_t(255);
        return r;
    };
    unsigned short* hbf  = (unsigned short*)alloc(sizeof(unsigned short) * (size_t)n * 128);
    unsigned short* bufB = (unsigned short*)alloc(sizeof(unsigned short) * (size_t)n * 128);
    int*   cnt    = (int*)alloc(sizeof(int) * n);
    int*   offs   = (int*)alloc(sizeof(int) * (n + 1));
    int*   cursor = (int*)alloc(sizeof(int) * n);
    int*   csr    = (int*)alloc(sizeof(int) * e);
    float* dis    = (float*)alloc(sizeof(float) * n);
    float* stats  = (float*)alloc(sizeof(float) * 4 * NSLOT * 128);
    float* bn     = (float*)alloc(sizeof(float) * 512);  // a1,cc1,a2,cc2
    int*   chunkSum  = (int*)alloc(sizeof(int) * NCHUNK);
    int*   chunkBase = (int*)alloc(sizeof(int) * NCHUNK);
    unsigned short* wf1 = (unsigned short*)alloc(sizeof(unsigned short) * 32 * 64 * 8);
    unsigned short* wf2 = (unsigned short*)alloc(sizeof(unsigned short) * 32 * 64 * 8);
    unsigned short* wf3 = (unsigned short*)alloc(sizeof(unsigned short) * 16 * 64 * 8);
    float* ssum1 = stats,              *ssq1 = stats + NSLOT * 128;
    float* ssum2 = stats + 2 * NSLOT * 128, *ssq2 = stats + 3 * NSLOT * 128;
    float* a1 = bn, *cc1 = bn + 128, *a2 = bn + 256, *cc2 = bn + 384;

    int gb_n  = (n + 255) / 256;
    int gb_e  = (e + 255) / 256;
    int gb_gemm = (n + 31) / 32;
    int gb_agg = (n + 3) / 4;

    // graph preprocessing (shared by all 3 layers) + W fragment prep
    k_init<<<gb_n, 256, 0, stream>>>(cnt, stats, n);
    k_count<<<gb_e, 256, 0, stream>>>(edst, cnt, e);
    k_wprep3<<<80, 64, 0, stream>>>(W1, W2, W3, wf1, wf2, wf3);
    k_chunksum<<<NCHUNK / 256, 256, 0, stream>>>(cnt, chunkSum, n);
    k_chunkscan<<<1, NCHUNK, 0, stream>>>(chunkSum, chunkBase);
    k_chunkwrite<<<NCHUNK / 256, 256, 0, stream>>>(cnt, chunkBase, offs, cursor, dis, n, e);
    k_scatter<<<gb_e, 256, 0, stream>>>(esrc, edst, cursor, csr, e);

    // layer 1
    k_gemm<false, 128, false><<<gb_gemm, 256, 0, stream>>>(x, (const uint4*)wf1, dis, nullptr, nullptr, hbf, n);
    k_agg<128, true><<<gb_agg, 256, 0, stream>>>(hbf, offs, csr, dis, b1, bufB, ssum1, ssq1, n);
    k_bnparams<<<1, 128, 0, stream>>>(ssum1, ssq1, gamma1, beta1, a1, cc1, n);

    // layer 2
    k_gemm<true, 128, true><<<gb_gemm, 256, 0, stream>>>(bufB, (const uint4*)wf2, dis, a1, cc1, hbf, n);
    k_agg<128, true><<<gb_agg, 256, 0, stream>>>(hbf, offs, csr, dis, b2, bufB, ssum2, ssq2, n);
    k_bnparams<<<1, 128, 0, stream>>>(ssum2, ssq2, gamma2, beta2, a2, cc2, n);

    // layer 3 (no BN/ReLU after)
    k_gemm<true, 64, true><<<gb_gemm, 256, 0, stream>>>(bufB, (const uint4*)wf3, dis, a2, cc2, hbf, n);
    k_agg<64, false><<<gb_agg, 256, 0, stream>>>(hbf, offs, csr, dis, b3, out, nullptr, nullptr, n);
}

// Round 8
// 243.602 us; speedup vs baseline: 2.8833x; 1.0217x over previous
//
#include <hip/hip_runtime.h>
#include <hip/hip_bf16.h>

// GCN: 3 layers, N=50000 nodes, E=600000 edges, feats 128->128->128->64,
// BatchNorm+ReLU between layers. norm = dis[src]*dis[dst] factorized out.
// GEMMs on MFMA bf16 (fp32 accum); all intermediate buffers bf16; BN stats
// fused into k_agg epilogue (64-slot atomic partials). GEMM epilogue goes
// through LDS so global writes are coalesced uint4 rows.

#define NCHUNK 1024
#define NSLOT 64

typedef short bf16x8 __attribute__((ext_vector_type(8)));
typedef float f32x4 __attribute__((ext_vector_type(4)));

union FragU { uint4 u; bf16x8 f; };

static __device__ __forceinline__ float4 ld4(const float* p) {
    return *reinterpret_cast<const float4*>(p);
}

// pack two fp32 -> bf16x2 (RNE), memory order lo,hi
static __device__ __forceinline__ unsigned pk2(float lo, float hi) {
    __hip_bfloat162 h = __float22bfloat162_rn(make_float2(lo, hi));
    union { __hip_bfloat162 h2; unsigned u; } c;
    c.h2 = h;
    return c.u;
}
static __device__ __forceinline__ unsigned short bf1(float v) {
    return (unsigned short)(pk2(v, 0.f) & 0xffffu);
}
static __device__ __forceinline__ float bf_lo(unsigned u) { return __uint_as_float(u << 16); }
static __device__ __forceinline__ float bf_hi(unsigned u) { return __uint_as_float(u & 0xffff0000u); }

__global__ void k_init(int* __restrict__ cnt, float* __restrict__ stats, int n) {
    int i = blockIdx.x * 256 + threadIdx.x;
    if (i < n) cnt[i] = 0;
    if (i < 4 * NSLOT * 128) stats[i] = 0.f;   // ssum1, ssq1, ssum2, ssq2
}

__global__ void k_count(const int* __restrict__ dst, int* __restrict__ cnt, int e) {
    int i = blockIdx.x * 256 + threadIdx.x;
    if (i < e) atomicAdd(&cnt[dst[i]], 1);
}

// Stage 1: per-chunk sums of cnt. NCHUNK threads, chunk = contiguous run.
__global__ __launch_bounds__(256) void k_chunksum(const int* __restrict__ cnt,
                                                  int* __restrict__ chunkSum, int n) {
    int t = blockIdx.x * 256 + threadIdx.x;   // 0..NCHUNK-1
    int per = (n + NCHUNK - 1) / NCHUNK;
    int lo = t * per; if (lo > n) lo = n;
    int hi = lo + per; if (hi > n) hi = n;
    int s = 0;
    for (int i = lo; i < hi; ++i) s += cnt[i];
    chunkSum[t] = s;
}

// Stage 2 (fused scan+write): each of the 4 blocks redundantly scans all
// NCHUNK chunk sums in LDS (4 per thread + 256-scan), then writes
// offs/cursor/dis for its own 256 chunks.
__global__ __launch_bounds__(256) void k_chunkwrite(const int* __restrict__ cnt,
                                                    const int* __restrict__ chunkSum,
                                                    int* __restrict__ offs,
                                                    int* __restrict__ cursor,
                                                    float* __restrict__ dis,
                                                    int n, int e) {
    __shared__ int lbase[NCHUNK];
    __shared__ int lth[256];
    int t = threadIdx.x;
    int a0 = chunkSum[t * 4 + 0], a1 = chunkSum[t * 4 + 1];
    int a2 = chunkSum[t * 4 + 2], a3 = chunkSum[t * 4 + 3];
    lth[t] = a0 + a1 + a2 + a3;
    __syncthreads();
    for (int off = 1; off < 256; off <<= 1) {
        int v = (t >= off) ? lth[t - off] : 0;
        __syncthreads();
        lth[t] += v;
        __syncthreads();
    }
    int base = (t == 0) ? 0 : lth[t - 1];
    lbase[t * 4 + 0] = base;
    lbase[t * 4 + 1] = base + a0;
    lbase[t * 4 + 2] = base + a0 + a1;
    lbase[t * 4 + 3] = base + a0 + a1 + a2;
    __syncthreads();
    int cid = blockIdx.x * 256 + t;
    int per = (n + NCHUNK - 1) / NCHUNK;
    int lo = cid * per; if (lo > n) lo = n;
    int hi = lo + per; if (hi > n) hi = n;
    int run = lbase[cid];
    for (int i = lo; i < hi; ++i) {
        offs[i] = run;
        cursor[i] = run;
        int c = cnt[i];
        dis[i] = rsqrtf((float)(c + 1));
        run += c;
    }
    if (cid == 0) offs[n] = e;
}

__global__ void k_scatter(const int* __restrict__ src, const int* __restrict__ dst,
                          int* __restrict__ cursor, int* __restrict__ csr, int e) {
    int i = blockIdx.x * 256 + threadIdx.x;
    if (i < e) {
        int p = atomicAdd(&cursor[dst[i]], 1);
        csr[p] = src[i];
    }
}

// Pre-fragment W1,W2,W3 into MFMA B-operand order (bf16), one dispatch.
// Frag f = t*4+kk; lane l holds B[k = kk*32+(l>>4)*8+j][col = t*16+(l&15)].
__global__ __launch_bounds__(64) void k_wprep3(const float* __restrict__ W1,
                                               const float* __restrict__ W2,
                                               const float* __restrict__ W3,
                                               unsigned short* __restrict__ wf1,
                                               unsigned short* __restrict__ wf2,
                                               unsigned short* __restrict__ wf3) {
    int b = blockIdx.x;
    const float* W; unsigned short* Wf; int NC; int blk;
    if (b < 32)      { W = W1; Wf = wf1; NC = 128; blk = b; }
    else if (b < 64) { W = W2; Wf = wf2; NC = 128; blk = b - 32; }
    else             { W = W3; Wf = wf3; NC = 64;  blk = b - 64; }
    int kk = blk & 3;
    int l = threadIdx.x;
    int col = (blk >> 2) * 16 + (l & 15);
    int k0 = kk * 32 + (l >> 4) * 8;
    unsigned short* dst = &Wf[((size_t)blk * 64 + l) * 8];
#pragma unroll
    for (int j = 0; j < 8; ++j)
        dst[j] = bf1(W[(size_t)(k0 + j) * NC + col]);
}

// out[row][col] = bf16( dis[row] * sum_k in'(row,k) * W[k][col] )
// in'(row,k) = TRANS ? relu(in*ta[k]+tc[k]) : in.  INBF: input rows are bf16.
//
// MFMA 16x16x32 bf16. Block: 32 rows x NC cols, 256 threads = 4 waves.
// Wave w: rows (w>>1)*16..+16, col-half (w&1)*NC/2. A staged bf16 in LDS
// with XOR swizzle byte^=(row&7)<<4 (G4). B from pre-fragmented Wf.
// Epilogue: acc -> LDS [32][NC+8] (pad -> 2-way banks, free) -> coalesced
// uint4 row stores (was 16 scalar u16 stores/thread).
template <bool TRANS, int NC, bool INBF>
__global__ __launch_bounds__(256) void k_gemm(const void* __restrict__ inv,
                                              const uint4* __restrict__ Wf,
                                              const float* __restrict__ dis,
                                              const float* __restrict__ ta,
                                              const float* __restrict__ tc,
                                              unsigned short* __restrict__ out, int n) {
    constexpr int TPW = NC / 32;          // 16-col tiles per wave: 4 or 2
    constexpr int PADC = NC + 8;          // padded u16 row stride (272/144 B: 16B-aligned)
    constexpr int SHN = (32 * PADC > 32 * 128) ? 32 * PADC : 32 * 128;
    __shared__ unsigned short sh[SHN];
    const int tid = threadIdx.x;
    const int row0 = blockIdx.x * 32;

    if constexpr (INBF) {
        const unsigned short* in = (const unsigned short*)inv;
#pragma unroll
        for (int it = 0; it < 2; ++it) {
            int flat = it * 256 + tid;
            int r = flat >> 4, j = flat & 15;     // j indexes uint4 (8 bf16)
            int grow = row0 + r;
            uint4 v = make_uint4(0, 0, 0, 0);
            if (grow < n) v = *reinterpret_cast<const uint4*>(&in[(size_t)grow * 128 + j * 8]);
            if (TRANS) {
                int f = j * 8;
                float4 A0 = ld4(&ta[f]), A1 = ld4(&ta[f + 4]);
                float4 C0 = ld4(&tc[f]), C1 = ld4(&tc[f + 4]);
                v.x = pk2(fmaxf(bf_lo(v.x) * A0.x + C0.x, 0.f),
                          fmaxf(bf_hi(v.x) * A0.y + C0.y, 0.f));
                v.y = pk2(fmaxf(bf_lo(v.y) * A0.z + C0.z, 0.f),
                          fmaxf(bf_hi(v.y) * A0.w + C0.w, 0.f));
                v.z = pk2(fmaxf(bf_lo(v.z) * A1.x + C1.x, 0.f),
                          fmaxf(bf_hi(v.z) * A1.y + C1.y, 0.f));
                v.w = pk2(fmaxf(bf_lo(v.w) * A1.z + C1.z, 0.f),
                          fmaxf(bf_hi(v.w) * A1.w + C1.w, 0.f));
            }
            int byte = r * 256 + ((j * 16) ^ ((r & 7) << 4));
            *reinterpret_cast<uint4*>(reinterpret_cast<char*>(sh) + byte) = v;
        }
    } else {
        const float* in = (const float*)inv;
#pragma unroll
        for (int it = 0; it < 4; ++it) {
            int flat = it * 256 + tid;
            int r = flat >> 5, j4 = flat & 31;
            int grow = row0 + r;
            float4 v = make_float4(0.f, 0.f, 0.f, 0.f);
            if (grow < n) v = ld4(&in[(size_t)grow * 128 + j4 * 4]);
            if (TRANS) {
                int f = j4 * 4;
                float4 A = ld4(&ta[f]);
                float4 C = ld4(&tc[f]);
                v.x = fmaxf(v.x * A.x + C.x, 0.f);
                v.y = fmaxf(v.y * A.y + C.y, 0.f);
                v.z = fmaxf(v.z * A.z + C.z, 0.f);
                v.w = fmaxf(v.w * A.w + C.w, 0.f);
            }
            int byte = r * 256 + ((j4 * 8) ^ ((r & 7) << 4));
            *reinterpret_cast<uint2*>(reinterpret_cast<char*>(sh) + byte) =
                make_uint2(pk2(v.x, v.y), pk2(v.z, v.w));
        }
    }
    __syncthreads();

    const int l = tid & 63, w = tid >> 6;
    const int l15 = l & 15, g = l >> 4;
    const int rhalf = (w >> 1) * 16;          // LDS row offset: 0 or 16
    const int tbase = (w & 1) * TPW;          // col-tile offset

    f32x4 acc[TPW];
#pragma unroll
    for (int t = 0; t < TPW; ++t) acc[t] = (f32x4){0.f, 0.f, 0.f, 0.f};

    const int arow = rhalf + l15;
    const char* xb = reinterpret_cast<const char*>(sh) + arow * 256;
    const int aswz = (arow & 7) << 4;

#pragma unroll
    for (int kk = 0; kk < 4; ++kk) {
        FragU a;
        a.u = *reinterpret_cast<const uint4*>(xb + ((kk * 64 + g * 16) ^ aswz));
#pragma unroll
        for (int t = 0; t < TPW; ++t) {
            FragU b;
            b.u = Wf[(size_t)((tbase + t) * 4 + kk) * 64 + l];
            acc[t] = __builtin_amdgcn_mfma_f32_16x16x32_bf16(a.f, b.f, acc[t], 0, 0, 0);
        }
    }

    // epilogue: D[row = g*4+r][col = l15] per tile -> LDS -> coalesced stores
    const int rbase = row0 + rhalf + g * 4;
    float dv[4];
#pragma unroll
    for (int r = 0; r < 4; ++r) {
        int rr = rbase + r;
        dv[r] = (rr < n) ? dis[rr] : 0.f;
    }
    __syncthreads();   // all waves done reading staged A before overwrite
#pragma unroll
    for (int t = 0; t < TPW; ++t) {
        int col = (tbase + t) * 16 + l15;
#pragma unroll
        for (int r = 0; r < 4; ++r) {
            int lrow = rhalf + g * 4 + r;
            sh[lrow * PADC + col] = bf1(acc[t][r] * dv[r]);
        }
    }
    __syncthreads();
    constexpr int U4R = NC / 8;           // uint4 per output row
#pragma unroll
    for (int it = 0; it < (32 * U4R) / 256; ++it) {
        int flat = it * 256 + tid;
        int row = flat / U4R, j = flat % U4R;
        int grow = row0 + row;
        if (grow < n) {
            uint4 v = *reinterpret_cast<const uint4*>(&sh[row * PADC + j * 8]);
            *reinterpret_cast<uint4*>(&out[(size_t)grow * NC + j * 8]) = v;
        }
    }
}

// One wave per node: h[i] = dis[i] * (hs[i] + sum_{src in(i)} hs[src]) + bias.
// hs bf16. NC=128: writes bf16 + fused BN column stats (LDS reduce, 64-slot
// atomic partials). NC=64: writes fp32 to d_out, no stats.
template <int NC, bool STATS>
__global__ __launch_bounds__(256) void k_agg(const unsigned short* __restrict__ hs,
                                             const int* __restrict__ offs,
                                             const int* __restrict__ csr,
                                             const float* __restrict__ dis,
                                             const float* __restrict__ bias,
                                             void* __restrict__ outv,
                                             float* __restrict__ ssum,
                                             float* __restrict__ ssq, int n) {
    int wave = threadIdx.x >> 6, lane = threadIdx.x & 63;
    int node = blockIdx.x * 4 + wave;
    const int half = lane >> 5, l32 = lane & 31;

    if (NC == 128) {
        int e0 = 0, e1 = 0;
        if (node < n) { e0 = offs[node]; e1 = offs[node + 1]; }
        const uint2* hp = reinterpret_cast<const uint2*>(hs);   // 32 uint2 per row
        float4 a0 = make_float4(0.f, 0.f, 0.f, 0.f);
        float4 a1 = a0, a2 = a0, a3 = a0;
        if (half == 0 && node < n) {
            uint2 w = hp[(size_t)node * 32 + l32];              // self-loop
            a0 = make_float4(bf_lo(w.x), bf_hi(w.x), bf_lo(w.y), bf_hi(w.y));
        }
        int e = e0;
        for (; e + 8 <= e1; e += 8) {
            int i0 = csr[e + 0 + half];
            int i1 = csr[e + 2 + half];
            int i2 = csr[e + 4 + half];
            int i3 = csr[e + 6 + half];
            uint2 w0 = hp[(size_t)i0 * 32 + l32];
            uint2 w1 = hp[(size_t)i1 * 32 + l32];
            uint2 w2 = hp[(size_t)i2 * 32 + l32];
            uint2 w3 = hp[(size_t)i3 * 32 + l32];
            a0.x += bf_lo(w0.x); a0.y += bf_hi(w0.x); a0.z += bf_lo(w0.y); a0.w += bf_hi(w0.y);
            a1.x += bf_lo(w1.x); a1.y += bf_hi(w1.x); a1.z += bf_lo(w1.y); a1.w += bf_hi(w1.y);
            a2.x += bf_lo(w2.x); a2.y += bf_hi(w2.x); a2.z += bf_lo(w2.y); a2.w += bf_hi(w2.y);
            a3.x += bf_lo(w3.x); a3.y += bf_hi(w3.x); a3.z += bf_lo(w3.y); a3.w += bf_hi(w3.y);
        }
        for (; e + 2 <= e1; e += 2) {
            int i0 = csr[e + half];
            uint2 w0 = hp[(size_t)i0 * 32 + l32];
            a0.x += bf_lo(w0.x); a0.y += bf_hi(w0.x); a0.z += bf_lo(w0.y); a0.w += bf_hi(w0.y);
        }
        if (e < e1 && half == 0) {
            int i0 = csr[e];
            uint2 w0 = hp[(size_t)i0 * 32 + l32];
            a0.x += bf_lo(w0.x); a0.y += bf_hi(w0.x); a0.z += bf_lo(w0.y); a0.w += bf_hi(w0.y);
        }
        a0.x += a1.x + a2.x + a3.x;
        a0.y += a1.y + a2.y + a3.y;
        a0.z += a1.z + a2.z + a3.z;
        a0.w += a1.w + a2.w + a3.w;
        a0.x += __shfl_down(a0.x, 32);
        a0.y += __shfl_down(a0.y, 32);
        a0.z += __shfl_down(a0.z, 32);
        a0.w += __shfl_down(a0.w, 32);
        float4 oV = make_float4(0.f, 0.f, 0.f, 0.f);
        if (half == 0 && node < n) {
            float d = dis[node];
            float4 b = ld4(&bias[l32 * 4]);
            oV = make_float4(d * a0.x + b.x, d * a0.y + b.y,
                             d * a0.z + b.z, d * a0.w + b.w);
            uint2 w = make_uint2(pk2(oV.x, oV.y), pk2(oV.z, oV.w));
            reinterpret_cast<uint2*>(outv)[(size_t)node * 32 + l32] = w;
        }
        if constexpr (STATS) {
            __shared__ float ls[4][128];
            __shared__ float ls2[4][128];
            if (half == 0) {
                int c = l32 * 4;
                ls[wave][c + 0] = oV.x; ls2[wave][c + 0] = oV.x * oV.x;
                ls[wave][c + 1] = oV.y; ls2[wave][c + 1] = oV.y * oV.y;
                ls[wave][c + 2] = oV.z; ls2[wave][c + 2] = oV.z * oV.z;
                ls[wave][c + 3] = oV.w; ls2[wave][c + 3] = oV.w * oV.w;
            }
            __syncthreads();
            int t = threadIdx.x;
            int slot = (blockIdx.x & (NSLOT - 1)) * 128;
            if (t < 128) {
                float s = ls[0][t] + ls[1][t] + ls[2][t] + ls[3][t];
                atomicAdd(&ssum[slot + t], s);
            } else {
                int c = t - 128;
                float s2 = ls2[0][c] + ls2[1][c] + ls2[2][c] + ls2[3][c];
                atomicAdd(&ssq[slot + c], s2);
            }
        }
    } else {
        if (node >= n) return;
        int e0 = offs[node], e1 = offs[node + 1];
        const unsigned* hp = reinterpret_cast<const unsigned*>(hs);  // 32 uints per row
        float2 a0 = make_float2(0.f, 0.f);
        float2 a1 = a0, a2 = a0, a3 = a0;
        if (half == 0) {
            unsigned w = hp[(size_t)node * 32 + l32];            // self-loop
            a0 = make_float2(bf_lo(w), bf_hi(w));
        }
        int e = e0;
        for (; e + 8 <= e1; e += 8) {
            int i0 = csr[e + 0 + half];
            int i1 = csr[e + 2 + half];
            int i2 = csr[e + 4 + half];
            int i3 = csr[e + 6 + half];
            unsigned w0 = hp[(size_t)i0 * 32 + l32];
            unsigned w1 = hp[(size_t)i1 * 32 + l32];
            unsigned w2 = hp[(size_t)i2 * 32 + l32];
            unsigned w3 = hp[(size_t)i3 * 32 + l32];
            a0.x += bf_lo(w0); a0.y += bf_hi(w0);
            a1.x += bf_lo(w1); a1.y += bf_hi(w1);
            a2.x += bf_lo(w2); a2.y += bf_hi(w2);
            a3.x += bf_lo(w3); a3.y += bf_hi(w3);
        }
        for (; e + 2 <= e1; e += 2) {
            int i0 = csr[e + half];
            unsigned w0 = hp[(size_t)i0 * 32 + l32];
            a0.x += bf_lo(w0); a0.y += bf_hi(w0);
        }
        if (e < e1 && half == 0) {
            int i0 = csr[e];
            unsigned w0 = hp[(size_t)i0 * 32 + l32];
            a0.x += bf_lo(w0); a0.y += bf_hi(w0);
        }
        a0.x += a1.x + a2.x + a3.x;
        a0.y += a1.y + a2.y + a3.y;
        a0.x += __shfl_down(a0.x, 32);
        a0.y += __shfl_down(a0.y, 32);
        if (half == 0) {
            float d = dis[node];
            float2 o = make_float2(d * a0.x + bias[l32 * 2],
                                   d * a0.y + bias[l32 * 2 + 1]);
            reinterpret_cast<float2*>(outv)[(size_t)node * 32 + l32] = o;
        }
    }
}

// Reduce 64-slot partials -> BN affine params a, cc.
__global__ void k_bnparams(const float* __restrict__ ssum, const float* __restrict__ ssq,
                           const float* __restrict__ gamma, const float* __restrict__ beta,
                           float* __restrict__ a, float* __restrict__ cc, int n) {
    int c = threadIdx.x;
    if (c < 128) {
        float s = 0.f, s2 = 0.f;
        for (int k = 0; k < NSLOT; ++k) {
            s += ssum[k * 128 + c];
            s2 += ssq[k * 128 + c];
        }
        float inv_n = 1.0f / (float)n;
        float mean = s * inv_n;
        float var = s2 * inv_n - mean * mean;
        float sc = gamma[c] * rsqrtf(var + 1e-5f);
        a[c] = sc;
        cc[c] = beta[c] - mean * sc;
    }
}

extern "C" void kernel_launch(void* const* d_in, const int* in_sizes, int n_in,
                              void* d_out, int out_size, void* d_ws, size_t ws_size,
                              hipStream_t stream) {
    const float* x      = (const float*)d_in[0];
    const int*   ei     = (const int*)d_in[1];     // [2,E] row-major: src then dst
    const float* W1     = (const float*)d_in[2];
    const float* b1     = (const float*)d_in[3];
    const float* gamma1 = (const float*)d_in[4];
    const float* beta1  = (const float*)d_in[5];
    const float* W2     = (const float*)d_in[6];
    const float* b2     = (const float*)d_in[7];
    const float* gamma2 = (const float*)d_in[8];
    const float* beta2  = (const float*)d_in[9];
    const float* W3     = (const float*)d_in[10];
    const float* b3     = (const float*)d_in[11];
    float* out = (float*)d_out;

    const int n = in_sizes[0] / 128;       // 50000
    const int e = in_sizes[1] / 2;         // 600000
    const int* esrc = ei;
    const int* edst = ei + e;

    // workspace layout (256B aligned chunks)
    char* p = (char*)d_ws;
    auto alloc = [&](size_t bytes) {
        void* r = p;
        p += (bytes + 255) & ~size_t(255);
        return r;
    };
    unsigned short* hbf  = (unsigned short*)alloc(sizeof(unsigned short) * (size_t)n * 128);
    unsigned short* bufB = (unsigned short*)alloc(sizeof(unsigned short) * (size_t)n * 128);
    int*   cnt    = (int*)alloc(sizeof(int) * n);
    int*   offs   = (int*)alloc(sizeof(int) * (n + 1));
    int*   cursor = (int*)alloc(sizeof(int) * n);
    int*   csr    = (int*)alloc(sizeof(int) * e);
    float* dis    = (float*)alloc(sizeof(float) * n);
    float* stats  = (float*)alloc(sizeof(float) * 4 * NSLOT * 128);
    float* bn     = (float*)alloc(sizeof(float) * 512);  // a1,cc1,a2,cc2
    int*   chunkSum  = (int*)alloc(sizeof(int) * NCHUNK);
    unsigned short* wf1 = (unsigned short*)alloc(sizeof(unsigned short) * 32 * 64 * 8);
    unsigned short* wf2 = (unsigned short*)alloc(sizeof(unsigned short) * 32 * 64 * 8);
    unsigned short* wf3 = (unsigned short*)alloc(sizeof(unsigned short) * 16 * 64 * 8);
    float* ssum1 = stats,                   *ssq1 = stats + NSLOT * 128;
    float* ssum2 = stats + 2 * NSLOT * 128, *ssq2 = stats + 3 * NSLOT * 128;
    float* a1 = bn, *cc1 = bn + 128, *a2 = bn + 256, *cc2 = bn + 384;

    int gb_n  = (n + 255) / 256;
    int gb_e  = (e + 255) / 256;
    int gb_gemm = (n + 31) / 32;
    int gb_agg = (n + 3) / 4;

    // graph preprocessing (shared by all 3 layers) + W fragment prep
    k_init<<<gb_n, 256, 0, stream>>>(cnt, stats, n);
    k_count<<<gb_e, 256, 0, stream>>>(edst, cnt, e);
    k_wprep3<<<80, 64, 0, stream>>>(W1, W2, W3, wf1, wf2, wf3);
    k_chunksum<<<NCHUNK / 256, 256, 0, stream>>>(cnt, chunkSum, n);
    k_chunkwrite<<<NCHUNK / 256, 256, 0, stream>>>(cnt, chunkSum, offs, cursor, dis, n, e);
    k_scatter<<<gb_e, 256, 0, stream>>>(esrc, edst, cursor, csr, e);

    // layer 1
    k_gemm<false, 128, false><<<gb_gemm, 256, 0, stream>>>(x, (const uint4*)wf1, dis, nullptr, nullptr, hbf, n);
    k_agg<128, true><<<gb_agg, 256, 0, stream>>>(hbf, offs, csr, dis, b1, bufB, ssum1, ssq1, n);
    k_bnparams<<<1, 128, 0, stream>>>(ssum1, ssq1, gamma1, beta1, a1, cc1, n);

    // layer 2
    k_gemm<true, 128, true><<<gb_gemm, 256, 0, stream>>>(bufB, (const uint4*)wf2, dis, a1, cc1, hbf, n);
    k_agg<128, true><<<gb_agg, 256, 0, stream>>>(hbf, offs, csr, dis, b2, bufB, ssum2, ssq2, n);
    k_bnparams<<<1, 128, 0, stream>>>(ssum2, ssq2, gamma2, beta2, a2, cc2, n);

    // layer 3 (no BN/ReLU after)
    k_gemm<true, 64, true><<<gb_gemm, 256, 0, stream>>>(bufB, (const uint4*)wf3, dis, a2, cc2, hbf, n);
    k_agg<64, false><<<gb_agg, 256, 0, stream>>>(hbf, offs, csr, dis, b3, out, nullptr, nullptr, n);
}